// Round 9
// baseline (4797.352 us; speedup 1.0000x reference)
//
#include <hip/hip_runtime.h>
#include <hip/hip_bf16.h>

#define BB 4
#define NN 8192
#define CC 64
#define SS 2048
#define GG 32
#define C2V 128
#define HHV 512

typedef unsigned long long u64;
typedef unsigned int u32;

// ---------------------------------------------------------------- transpose fea (B,C,N)->(B,N,C)
__global__ void k_transpose_fea(const float* __restrict__ in, float* __restrict__ out) {
  __shared__ float tile[32][33];
  const int b = blockIdx.z;
  const int n0 = blockIdx.x * 32, c0 = blockIdx.y * 32;
  const int tx = threadIdx.x, ty = threadIdx.y;
  const float* src = in + (size_t)b * CC * NN;
#pragma unroll
  for (int i = 0; i < 32; i += 8)
    tile[ty + i][tx] = src[(size_t)(c0 + ty + i) * NN + n0 + tx];
  __syncthreads();
  float* dst = out + (size_t)b * NN * CC;
#pragma unroll
  for (int i = 0; i < 32; i += 8)
    dst[(size_t)(n0 + ty + i) * CC + c0 + tx] = tile[tx][ty + i];
}

// ---------------------------------------------------------------- FPS (v5)
// 512 thr = 8 waves, 16 pts/lane in named float4 regs. KEY FIX vs r6-r8: the
// compiler was REMATERIALIZING the loop-invariant coord loads from L2 every
// step (hence VGPR stuck at 48-68) -- asm-pinning each loaded float makes
// remat impossible, forcing true register residency (budget: launch_bounds
// (512,2) => 256 VGPR/wave).
// Per step: winner lane publishes {key, x,y,z, idx} to double-buffered LDS.
// Next step: all lanes pre-read slot (lane&7)'s coords in parallel with the
// key, 3x DPP key-reduce, then readfirstlane+readlane broadcast of the
// winner's coords (no global load, no bpermute chain on the critical path).
// Numerics = verified r5/r7/r8 chain: contract-off materialized squares, one
// correctly-rounded sqrtf per lane, exact f64 preimage floor of s's rounding
// interval for np's first-index tie-break among sqrt-collisions.
__global__ __launch_bounds__(512, 2) void k_fps(const float* __restrict__ pc, int* __restrict__ fps_idx) {
#pragma clang fp contract(off)
  const int b = blockIdx.x, tid = threadIdx.x;
  const int lane = tid & 63, wid = tid >> 6;
  const float* pb = pc + (size_t)b * 3 * NN;
  const float4* p4x = (const float4*)pb;
  const float4* p4y = (const float4*)(pb + NN);
  const float4* p4z = (const float4*)(pb + 2 * NN);
  float4 X0 = p4x[tid * 4 + 0], X1 = p4x[tid * 4 + 1], X2 = p4x[tid * 4 + 2], X3 = p4x[tid * 4 + 3];
  float4 Y0 = p4y[tid * 4 + 0], Y1 = p4y[tid * 4 + 1], Y2 = p4y[tid * 4 + 2], Y3 = p4y[tid * 4 + 3];
  float4 Z0 = p4z[tid * 4 + 0], Z1 = p4z[tid * 4 + 1], Z2 = p4z[tid * 4 + 2], Z3 = p4z[tid * 4 + 3];
  // pin: value becomes asm-produced -> cannot be rematerialized from memory
#define PIN4(V) asm volatile("" : "+v"((V).x), "+v"((V).y), "+v"((V).z), "+v"((V).w));
  PIN4(X0) PIN4(X1) PIN4(X2) PIN4(X3)
  PIN4(Y0) PIN4(Y1) PIN4(Y2) PIN4(Y3)
  PIN4(Z0) PIN4(Z1) PIN4(Z2) PIN4(Z3)
#undef PIN4
  float4 D0 = make_float4(1e20f, 1e20f, 1e20f, 1e20f);
  float4 D1 = D0, D2q = D0, D3 = D0;

  __shared__ u64 sK[2][8];
  __shared__ float4 sC[2][8];
  if (lane == 0) sK[0][wid] = 0ull;
  if (tid == 0) {
    sK[0][0] = ~0ull;
    sC[0][0] = make_float4(X0.x, Y0.x, Z0.x, __int_as_float(0));
  }
  __syncthreads();

#define DPPK64(K, CTL) { \
      u32 lo = (u32)(K), hi = (u32)((K) >> 32); \
      u32 lo2 = (u32)__builtin_amdgcn_update_dpp(0, (int)lo, CTL, 0xf, 0xf, false); \
      u32 hi2 = (u32)__builtin_amdgcn_update_dpp(0, (int)hi, CTL, 0xf, 0xf, false); \
      u64 k2 = ((u64)hi2 << 32) | (u64)lo2; if (k2 > (K)) (K) = k2; }
#define RMAXF(V, CTL) { \
      float t_ = __int_as_float(__builtin_amdgcn_update_dpp(0, __float_as_int(V), CTL, 0xf, 0xf, false)); \
      (V) = fmaxf((V), t_); }
#define RMINU(V, CTL) { \
      u32 t_ = (u32)__builtin_amdgcn_update_dpp(0, (int)(V), CTL, 0xf, 0xf, false); \
      (V) = min((V), t_); }

  for (int k = 0; k < SS; ++k) {
    const int p = k & 1, pn = p ^ 1;
    // ---- key + speculative coord read (parallel, independent LDS reads)
    u64 kk = sK[p][lane & 7];
    float4 cw = sC[p][lane & 7];
    DPPK64(kk, 0x121) DPPK64(kk, 0x122) DPPK64(kk, 0x124)
    const u32 wtid = 0xFFFFFFFFu - (u32)kk;           // winning tid (wave-uniform)
    const u32 ws = __builtin_amdgcn_readfirstlane(wtid >> 6);  // winner slot -> SGPR
    // broadcast winner coords from the lane that pre-read slot ws (lane ws holds it)
    const float cx = __uint_as_float(__builtin_amdgcn_readlane(__float_as_uint(cw.x), ws));
    const float cy = __uint_as_float(__builtin_amdgcn_readlane(__float_as_uint(cw.y), ws));
    const float cz = __uint_as_float(__builtin_amdgcn_readlane(__float_as_uint(cw.z), ws));
    const u32 gidx = __builtin_amdgcn_readlane(__float_as_uint(cw.w), ws);
    if (tid == 0) fps_idx[b * SS + k] = __float_as_int(__uint_as_float(gidx));

    // ---- squared-distance update (bitwise np: materialized squares, (t0+t1)+t2)
#define UPDC(XX, YY, ZZ, DD) { \
      float dx_ = (XX) - cx, dy_ = (YY) - cy, dz_ = (ZZ) - cz; \
      float t0_ = dx_ * dx_, t1_ = dy_ * dy_, t2_ = dz_ * dz_; \
      float s_ = (t0_ + t1_) + t2_; \
      (DD) = fminf((DD), s_); }
    UPDC(X0.x, Y0.x, Z0.x, D0.x) UPDC(X0.y, Y0.y, Z0.y, D0.y)
    UPDC(X0.z, Y0.z, Z0.z, D0.z) UPDC(X0.w, Y0.w, Z0.w, D0.w)
    UPDC(X1.x, Y1.x, Z1.x, D1.x) UPDC(X1.y, Y1.y, Z1.y, D1.y)
    UPDC(X1.z, Y1.z, Z1.z, D1.z) UPDC(X1.w, Y1.w, Z1.w, D1.w)
    UPDC(X2.x, Y2.x, Z2.x, D2q.x) UPDC(X2.y, Y2.y, Z2.y, D2q.y)
    UPDC(X2.z, Y2.z, Z2.z, D2q.z) UPDC(X2.w, Y2.w, Z2.w, D2q.w)
    UPDC(X3.x, Y3.x, Z3.x, D3.x) UPDC(X3.y, Y3.y, Z3.y, D3.y)
    UPDC(X3.z, Y3.z, Z3.z, D3.z) UPDC(X3.w, Y3.w, Z3.w, D3.w)
#undef UPDC

    // ---- per-lane max of squared dists, one correctly-rounded sqrt
    float m2 = fmaxf(
        fmaxf(fmaxf(fmaxf(D0.x, D0.y), fmaxf(D0.z, D0.w)),
              fmaxf(fmaxf(D1.x, D1.y), fmaxf(D1.z, D1.w))),
        fmaxf(fmaxf(fmaxf(D2q.x, D2q.y), fmaxf(D2q.z, D2q.w)),
              fmaxf(fmaxf(D3.x, D3.y), fmaxf(D3.z, D3.w))));
    float s = sqrtf(m2);

    // ---- in-wave 2-phase reduce: max s, then min tid among ties
    //      (tid order == point-index order: tid owns points [16t,16t+16))
    float sm = s;
    RMAXF(sm, 0x121) RMAXF(sm, 0x122) RMAXF(sm, 0x124) RMAXF(sm, 0x128)
    sm = fmaxf(sm, __shfl_xor(sm, 16, 64));
    sm = fmaxf(sm, __shfl_xor(sm, 32, 64));
    u32 encT = (s == sm) ? (u32)tid : 0xFFFFFFFFu;
    RMINU(encT, 0x121) RMINU(encT, 0x122) RMINU(encT, 0x124) RMINU(encT, 0x128)
    encT = min(encT, (u32)__shfl_xor((int)encT, 16, 64));
    encT = min(encT, (u32)__shfl_xor((int)encT, 32, 64));

    // ---- per-wave winner lane: exact preimage floor, first-index jsel,
    //      coord select, publish {key, coords, point idx}
    if ((u32)tid == encT) {
      u32 sbits = __float_as_uint(s);
      float spred = __uint_as_float(sbits - 1u);
      double M = ((double)spred + (double)s) * 0.5;
      double L = M * M;
      if (sbits & 1u) L = __longlong_as_double(__double_as_longlong(L) + 1ll);
      float Lf = (float)L;
      if ((double)Lf < L) Lf = __uint_as_float(__float_as_uint(Lf) + 1u);

      int jsel = 15; float sx = X3.w, sy = Y3.w, sz = Z3.w;
#define SELC(J, DD, XX, YY, ZZ) if ((DD) >= Lf) { jsel = J; sx = (XX); sy = (YY); sz = (ZZ); }
      SELC(14, D3.z, X3.z, Y3.z, Z3.z) SELC(13, D3.y, X3.y, Y3.y, Z3.y)
      SELC(12, D3.x, X3.x, Y3.x, Z3.x) SELC(11, D2q.w, X2.w, Y2.w, Z2.w)
      SELC(10, D2q.z, X2.z, Y2.z, Z2.z) SELC(9, D2q.y, X2.y, Y2.y, Z2.y)
      SELC(8, D2q.x, X2.x, Y2.x, Z2.x) SELC(7, D1.w, X1.w, Y1.w, Z1.w)
      SELC(6, D1.z, X1.z, Y1.z, Z1.z) SELC(5, D1.y, X1.y, Y1.y, Z1.y)
      SELC(4, D1.x, X1.x, Y1.x, Z1.x) SELC(3, D0.w, X0.w, Y0.w, Z0.w)
      SELC(2, D0.z, X0.z, Y0.z, Z0.z) SELC(1, D0.y, X0.y, Y0.y, Z0.y)
      SELC(0, D0.x, X0.x, Y0.x, Z0.x)
#undef SELC
      sK[pn][wid] = (((u64)__float_as_uint(s)) << 32) | (u64)(0xFFFFFFFFu - (u32)tid);
      sC[pn][wid] = make_float4(sx, sy, sz, __int_as_float(tid * 16 + jsel));
    }
    __syncthreads();  // single barrier per step (double-buffered slots)
  }
#undef DPPK64
#undef RMAXF
#undef RMINU
}

// ---------------------------------------------------------------- gather new_coor + out0
__global__ void k_gather(const float* __restrict__ pc, const int* __restrict__ fps_idx,
                         float* __restrict__ ncoor, float* __restrict__ out0) {
  int t = blockIdx.x * 256 + threadIdx.x;
  if (t >= BB * SS) return;
  int b = t / SS, s = t % SS;
  int id = fps_idx[t];
  const float* base = pc + (size_t)b * 3 * NN;
  float x = base[id], y = base[NN + id], z = base[2 * NN + id];
  ncoor[(size_t)t * 3] = x; ncoor[(size_t)t * 3 + 1] = y; ncoor[(size_t)t * 3 + 2] = z;
  size_t o = (size_t)b * 3 * SS + s;
  out0[o] = x; out0[o + SS] = y; out0[o + 2 * SS] = z;
}

// ---------------------------------------------------------------- kNN (k=32 within radius, fill with argmin)
// Distance replicates np's _sqdist bit-for-bit:
//   dot: np.einsum inner sum-of-products loop -> gcc -ffp-contract=fast -> FMA chain
//        acc = fma(a2,b2, fma(a1,b1, a0*b0))
//   norms: np.sum(x**2,-1) over a MATERIALIZED squares array -> pure sequential adds (no FMA)
//   d = ((-2*dot) + ||q||^2) + ||p||^2  (sequential adds, f32 throughout)
__global__ __launch_bounds__(256) void k_knn(const float* __restrict__ candp,
                                             const float* __restrict__ newc,
                                             int mode, int ncand, float r2,
                                             int* __restrict__ gidx) {
  __shared__ float cd[2048];
  __shared__ int ci[2048];
  __shared__ int hist[64];
  __shared__ int cnt, oc, binT, mlow;
  const int q = blockIdx.x, tid = threadIdx.x;
  const int b = q / SS;
  if (tid == 0) { cnt = 0; oc = 0; }
  if (tid < 64) hist[tid] = 0;
  __syncthreads();
  const float qx = newc[(size_t)q * 3], qy = newc[(size_t)q * 3 + 1], qz = newc[(size_t)q * 3 + 2];
  float qn;
  {
#pragma clang fp contract(off)
    qn = (qx * qx + qy * qy) + qz * qz;
  }
  const float sc = 64.0f / r2;
  const float* base = (mode == 0) ? candp + (size_t)b * 3 * NN : candp + (size_t)b * SS * 3;
  for (int i = tid; i < ncand; i += 256) {
    float x, y, z;
    if (mode == 0) { x = base[i]; y = base[NN + i]; z = base[2 * NN + i]; }
    else { x = base[3 * i]; y = base[3 * i + 1]; z = base[3 * i + 2]; }
    // FMA-chain dot (np einsum), contract-off norms (np materialized squares)
    float dot = fmaf(qz, z, fmaf(qy, y, qx * x));
    float d;
    {
#pragma clang fp contract(off)
      float pn = (x * x + y * y) + z * z;
      d = ((-2.0f * dot) + qn) + pn;
    }
    if (d <= r2) {
      int pp = atomicAdd(&cnt, 1);
      if (pp < 2048) { cd[pp] = d; ci[pp] = i; }
      float db = (d > 0.0f) ? d : 0.0f;
      atomicAdd(&hist[min(63, (int)(db * sc))], 1);
    }
  }
  __syncthreads();
  const int M = min(cnt, 2048);
  if (tid == 0) {
    if (M > 32) {
      int c = 0, t = 0;
      for (t = 0; t < 64; ++t) { if (c + hist[t] >= 32) break; c += hist[t]; }
      binT = t; mlow = c;
    } else binT = -1;
  }
  __syncthreads();
  int* out = gidx + (size_t)q * 32;
  if (binT < 0) {
    for (int j = tid; j < M; j += 256) out[atomicAdd(&oc, 1)] = ci[j];
    __syncthreads();
    if (tid == 0 && M < 32) {
      float bd = 1e30f; int bx = 0x7FFFFFFF;
      for (int j = 0; j < M; ++j)
        if (cd[j] < bd || (cd[j] == bd && ci[j] < bx)) { bd = cd[j]; bx = ci[j]; }
      for (int j = M; j < 32; ++j) out[j] = bx;
    }
  } else {
    const int bt = binT, m = mlow;
    for (int j = tid; j < M; j += 256) {
      float dbj = (cd[j] > 0.0f) ? cd[j] : 0.0f;
      int bin = min(63, (int)(dbj * sc));
      if (bin < bt) out[atomicAdd(&oc, 1)] = ci[j];
      else if (bin == bt) {
        int r = 0; const float dj = cd[j]; const int ij = ci[j];
        for (int kk = 0; kk < M; ++kk) {
          float dbk = (cd[kk] > 0.0f) ? cd[kk] : 0.0f;
          if (min(63, (int)(dbk * sc)) == bt &&
              (cd[kk] < dj || (cd[kk] == dj && ci[kk] < ij))) ++r;
        }
        if (m + r < 32) out[m + r] = ci[j];
      }
    }
  }
}

// ---------------------------------------------------------------- grouped MLP + max  (out 128 ch)
template <int FDIM>
__global__ __launch_bounds__(256) void k_group_mlp(
    const float* __restrict__ fea, const int* __restrict__ gidx,
    const float* __restrict__ newc, const float* __restrict__ candp,
    int mode, int ncand, float radius,
    const float* __restrict__ wp, float* __restrict__ outf) {
  constexpr int CP4 = FDIM + 4;     // padded cols (67->68, 131->132)
  constexpr int NC4 = CP4 / 4;
  __shared__ float4 g4[2][32][NC4];
  __shared__ int sidx[2][32];
  __shared__ float sq[2][3];
  __shared__ float pf[2][4][128];
  const int tid = threadIdx.x;
  const int rs = tid >> 7, tl = tid & 127;
  const int dt = tl & 31, et = tl >> 5;
  const int d0 = dt * 4, e0 = et * 8;
  const int row0 = blockIdx.x * 16;
  for (int rp = 0; rp < 16; rp += 2) {
    const int row = row0 + rp + rs;
    if (tl < 32) sidx[rs][tl] = gidx[(size_t)row * 32 + tl];
    if (tl < 3) sq[rs][tl] = newc[(size_t)row * 3 + tl];
    __syncthreads();
    const int bb2 = row / SS;
    const float* fb = fea + (size_t)bb2 * ncand * FDIM;
    const float* cb = (mode == 0) ? candp + (size_t)bb2 * 3 * NN
                                  : candp + (size_t)bb2 * SS * 3;
    float* gf = (float*)&g4[rs][0][0];
    for (int qq = tl; qq < 32 * CP4; qq += 128) {
      int e = qq / CP4, c = qq - e * CP4;
      int id = sidx[rs][e];
      float v;
      if (c < FDIM) v = fb[(size_t)id * FDIM + c];
      else if (c < FDIM + 3) {
        int comp = c - FDIM;
        float pcv = (mode == 0) ? cb[(size_t)comp * NN + id] : cb[(size_t)id * 3 + comp];
        v = (pcv - sq[rs][comp]) / radius;
      } else v = 0.0f;
      gf[qq] = v;
    }
    __syncthreads();
    float acc[4][8];
#pragma unroll
    for (int i = 0; i < 4; ++i)
#pragma unroll
      for (int j = 0; j < 8; ++j) acc[i][j] = 0.0f;
    const float4* w4 = (const float4*)wp;
    for (int c4 = 0; c4 < NC4; ++c4) {
      float4 wv[4], gv[8];
#pragma unroll
      for (int i = 0; i < 4; ++i) wv[i] = w4[(size_t)(d0 + i) * NC4 + c4];
#pragma unroll
      for (int j = 0; j < 8; ++j) gv[j] = g4[rs][e0 + j][c4];
#pragma unroll
      for (int i = 0; i < 4; ++i)
#pragma unroll
        for (int j = 0; j < 8; ++j) {
          acc[i][j] += wv[i].x * gv[j].x;
          acc[i][j] += wv[i].y * gv[j].y;
          acc[i][j] += wv[i].z * gv[j].z;
          acc[i][j] += wv[i].w * gv[j].w;
        }
    }
#pragma unroll
    for (int i = 0; i < 4; ++i) {
      float m = acc[i][0];
#pragma unroll
      for (int j = 1; j < 8; ++j) m = fmaxf(m, acc[i][j]);
      pf[rs][et][d0 + i] = m;
    }
    __syncthreads();
    {
      const int d = tid & 127, r2s = tid >> 7;
      const int rowW = row0 + rp + r2s;
      float m = fmaxf(fmaxf(pf[r2s][0][d], pf[r2s][1][d]),
                      fmaxf(pf[r2s][2][d], pf[r2s][3][d]));
      outf[(size_t)rowW * 128 + d] = fmaxf(m, 0.0f);
    }
    __syncthreads();
  }
}

// ---------------------------------------------------------------- dense GEMM: Out = relu(A(M,K) * W(N,K)^T [+ Id])
template <bool RESID>
__global__ __launch_bounds__(256) void k_dense(
    const float* __restrict__ A, const float* __restrict__ W,
    const float* __restrict__ Id, float* __restrict__ Out,
    int K, int Ntot) {
  __shared__ float4 sa[64][17], sb[64][17];
  const int m0 = blockIdx.x * 64, n0 = blockIdx.y * 64;
  const int tid = threadIdx.x;
  const int mt = tid & 15, nt = tid >> 4;
  float acc[4][4];
#pragma unroll
  for (int i = 0; i < 4; ++i)
#pragma unroll
    for (int j = 0; j < 4; ++j) acc[i][j] = 0.0f;
  for (int kc = 0; kc < K; kc += 64) {
    for (int q2 = tid; q2 < 2048; q2 += 256) {
      int half = q2 >> 10, qq = q2 & 1023;
      int r = qq >> 4, c = qq & 15;
      const float* src = half ? (W + (size_t)(n0 + r) * K + kc + c * 4)
                              : (A + (size_t)(m0 + r) * K + kc + c * 4);
      float4 v = *(const float4*)src;
      if (half) sb[r][c] = v; else sa[r][c] = v;
    }
    __syncthreads();
#pragma unroll
    for (int c = 0; c < 16; ++c) {
      const int ks = (c + mt + nt) & 15;  // swizzle to break LDS bank conflicts
      float4 av[4], bv[4];
#pragma unroll
      for (int i = 0; i < 4; ++i) av[i] = sa[mt * 4 + i][ks];
#pragma unroll
      for (int j = 0; j < 4; ++j) bv[j] = sb[nt * 4 + j][ks];
#pragma unroll
      for (int i = 0; i < 4; ++i)
#pragma unroll
        for (int j = 0; j < 4; ++j) {
          acc[i][j] += av[i].x * bv[j].x;
          acc[i][j] += av[i].y * bv[j].y;
          acc[i][j] += av[i].z * bv[j].z;
          acc[i][j] += av[i].w * bv[j].w;
        }
    }
    __syncthreads();
  }
#pragma unroll
  for (int i = 0; i < 4; ++i)
#pragma unroll
    for (int j = 0; j < 4; ++j) {
      size_t o = (size_t)(m0 + mt * 4 + i) * Ntot + n0 + nt * 4 + j;
      float v = acc[i][j];
      if (RESID) v += Id[o];
      Out[o] = fmaxf(v, 0.0f);
    }
}

// ---------------------------------------------------------------- pad weights rows to 4-aligned cols
__global__ void k_pad_w(const float* __restrict__ src, float* __restrict__ dst,
                        int rows, int cin, int cp4) {
  int t = blockIdx.x * 256 + threadIdx.x;
  if (t >= rows * cp4) return;
  int r = t / cp4, c = t - r * cp4;
  dst[t] = (c < cin) ? src[(size_t)r * cin + c] : 0.0f;
}

// ---------------------------------------------------------------- out1 transpose (B*S,128) -> (B,128,S)
__global__ void k_out1_t(const float* __restrict__ in, float* __restrict__ out) {
  __shared__ float tile[32][33];
  const int b = blockIdx.z;
  const int s0 = blockIdx.x * 32, d0 = blockIdx.y * 32;
  const int tx = threadIdx.x, ty = threadIdx.y;
#pragma unroll
  for (int i = 0; i < 32; i += 8)
    tile[ty + i][tx] = in[(size_t)(b * SS + s0 + ty + i) * 128 + d0 + tx];
  __syncthreads();
#pragma unroll
  for (int i = 0; i < 32; i += 8)
    out[(size_t)(b * 128 + d0 + ty + i) * SS + s0 + tx] = tile[tx][ty + i];
}

// ----------------------------------------------------------------
extern "C" void kernel_launch(void* const* d_in, const int* in_sizes, int n_in,
                              void* d_out, int out_size, void* d_ws, size_t ws_size,
                              hipStream_t stream) {
  const float* pc    = (const float*)d_in[0];
  const float* pfea  = (const float*)d_in[1];
  const float* w_sa  = (const float*)d_in[2];
  const float* w_la1 = (const float*)d_in[3];
  const float* w1_1  = (const float*)d_in[4];
  const float* w2_1  = (const float*)d_in[5];
  const float* w_la2 = (const float*)d_in[6];
  const float* w1_2  = (const float*)d_in[7];
  const float* w2_2  = (const float*)d_in[8];
  float* out0 = (float*)d_out;
  float* out1 = out0 + (size_t)BB * 3 * SS;

  char* wsp = (char*)d_ws;
  size_t off = 0;
  auto alloc = [&](size_t bytes) -> void* {
    void* p = wsp + off;
    off = (off + bytes + 255) & ~(size_t)255;
    return p;
  };
  float* hbuf = (float*)alloc((size_t)BB * SS * HHV * 4);  // 16 MB; also aliased as feaT (disjoint in time)
  float* feaT = hbuf;                                      // 8 MB needed, used only before hbuf
  int*   fpsi = (int*)alloc((size_t)BB * SS * 4);
  float* ncoor = (float*)alloc((size_t)BB * SS * 3 * 4);
  int*   gi = (int*)alloc((size_t)BB * SS * GG * 4);
  float* fa = (float*)alloc((size_t)BB * SS * C2V * 4);
  float* fb = (float*)alloc((size_t)BB * SS * C2V * 4);
  float* wsap = (float*)alloc(128 * 68 * 4);
  float* wla1p = (float*)alloc(128 * 132 * 4);
  float* wla2p = (float*)alloc(128 * 132 * 4);

  k_pad_w<<<dim3((128 * 68 + 255) / 256), dim3(256), 0, stream>>>(w_sa, wsap, 128, 67, 68);
  k_pad_w<<<dim3((128 * 132 + 255) / 256), dim3(256), 0, stream>>>(w_la1, wla1p, 128, 131, 132);
  k_pad_w<<<dim3((128 * 132 + 255) / 256), dim3(256), 0, stream>>>(w_la2, wla2p, 128, 131, 132);

  k_transpose_fea<<<dim3(NN / 32, CC / 32, BB), dim3(32, 8), 0, stream>>>(pfea, feaT);
  k_fps<<<dim3(BB), dim3(512), 0, stream>>>(pc, fpsi);
  k_gather<<<dim3((BB * SS + 255) / 256), dim3(256), 0, stream>>>(pc, fpsi, ncoor, out0);

  // stage 1: group among original N points, r=0.2
  k_knn<<<dim3(BB * SS), dim3(256), 0, stream>>>(pc, ncoor, 0, NN, 0.04f, gi);
  k_group_mlp<64><<<dim3(BB * SS / 16), dim3(256), 0, stream>>>(feaT, gi, ncoor, pc, 0, NN, 0.2f, wsap, fa);

  // shared grouping for both inv-res blocks (same points, same radius 0.4)
  k_knn<<<dim3(BB * SS), dim3(256), 0, stream>>>(ncoor, ncoor, 1, SS, 0.16f, gi);

  // inv-res block 1
  k_group_mlp<128><<<dim3(BB * SS / 16), dim3(256), 0, stream>>>(fa, gi, ncoor, ncoor, 1, SS, 0.4f, wla1p, fb);
  k_dense<false><<<dim3(128, 8), dim3(256), 0, stream>>>(fb, w1_1, nullptr, hbuf, 128, 512);
  k_dense<true><<<dim3(128, 2), dim3(256), 0, stream>>>(hbuf, w2_1, fa, fb, 512, 128);

  // inv-res block 2
  k_group_mlp<128><<<dim3(BB * SS / 16), dim3(256), 0, stream>>>(fb, gi, ncoor, ncoor, 1, SS, 0.4f, wla2p, fa);
  k_dense<false><<<dim3(128, 8), dim3(256), 0, stream>>>(fa, w1_2, nullptr, hbuf, 128, 512);
  k_dense<true><<<dim3(128, 2), dim3(256), 0, stream>>>(hbuf, w2_2, fb, fa, 512, 128);

  k_out1_t<<<dim3(SS / 32, 128 / 32, BB), dim3(32, 8), 0, stream>>>(fa, out1);
}

// Round 10
// 4291.108 us; speedup vs baseline: 1.1180x; 1.1180x over previous
//
#include <hip/hip_runtime.h>
#include <hip/hip_bf16.h>

#define BB 4
#define NN 8192
#define CC 64
#define SS 2048
#define GG 32
#define C2V 128
#define HHV 512

typedef unsigned long long u64;
typedef unsigned int u32;

// ---------------------------------------------------------------- transpose fea (B,C,N)->(B,N,C)
__global__ void k_transpose_fea(const float* __restrict__ in, float* __restrict__ out) {
  __shared__ float tile[32][33];
  const int b = blockIdx.z;
  const int n0 = blockIdx.x * 32, c0 = blockIdx.y * 32;
  const int tx = threadIdx.x, ty = threadIdx.y;
  const float* src = in + (size_t)b * CC * NN;
#pragma unroll
  for (int i = 0; i < 32; i += 8)
    tile[ty + i][tx] = src[(size_t)(c0 + ty + i) * NN + n0 + tx];
  __syncthreads();
  float* dst = out + (size_t)b * NN * CC;
#pragma unroll
  for (int i = 0; i < 32; i += 8)
    dst[(size_t)(n0 + ty + i) * CC + c0 + tx] = tile[tx][ty + i];
}

// ---------------------------------------------------------------- FPS (v6: LDS-staged coords)
// The r6-r9 register-residency fight is over: hipcc rematerializes loop-invariant
// global loads no matter what (VGPR stuck at 48-68, ~60% per-CU VALU on reload
// overhead). Deterministic fix: stage all 8192x3 coords in static LDS (96 KB of
// the 160 KB/CU). 1024 thr = 16 waves; each lane re-reads its 8 points per step
// via 6 conflict-free lane-contiguous ds_read_b128; only D^2 (8 floats) lives in
// registers. Winner coords = same-address broadcast LDS read at decoded idx.
// Ownership: lane owns points {c*4096 + wid*256 + lane*4 + e}; per-wave key
// (s_bits<<32 | ~global_idx) max-reduced via DPP gives exact np first-index
// argmax. Numerics = verified r5/r7-r9 chain: contract-off materialized squares,
// one correctly-rounded sqrtf per lane, exact f64 preimage floor of s's
// rounding interval for ties among sqrt-rounding-colliding points.
__global__ __launch_bounds__(1024, 4) void k_fps(const float* __restrict__ pc, int* __restrict__ fps_idx) {
#pragma clang fp contract(off)
  __shared__ float lx[NN], ly[NN], lz[NN];
  __shared__ u64 sK[2][16];
  const int b = blockIdx.x, tid = threadIdx.x;
  const int lane = tid & 63, wid = tid >> 6;
  const float* pb = pc + (size_t)b * 3 * NN;
  {
    const float4* gx = (const float4*)pb;
    const float4* gy = (const float4*)(pb + NN);
    const float4* gz = (const float4*)(pb + 2 * NN);
    float4* sx = (float4*)lx; float4* sy = (float4*)ly; float4* sz = (float4*)lz;
    sx[tid] = gx[tid]; sx[tid + 1024] = gx[tid + 1024];
    sy[tid] = gy[tid]; sy[tid + 1024] = gy[tid + 1024];
    sz[tid] = gz[tid]; sz[tid + 1024] = gz[tid + 1024];
  }
  if (tid < 32) ((u64*)sK)[tid] = 0ull;
  if (tid == 0) sK[0][0] = ~0ull;   // step-0 winner: idx 0 (s-bits all-ones beats any)
  __syncthreads();

  const int fbase = wid * 64 + lane;              // float4 index of chunk 0
  const u32 ibase = (u32)(wid * 256 + lane * 4);  // global point index base
  float4 D0 = make_float4(1e20f, 1e20f, 1e20f, 1e20f);
  float4 D1 = D0;

#define DPPK64(K, CTL) { \
      u32 lo = (u32)(K), hi = (u32)((K) >> 32); \
      u32 lo2 = (u32)__builtin_amdgcn_update_dpp(0, (int)lo, CTL, 0xf, 0xf, false); \
      u32 hi2 = (u32)__builtin_amdgcn_update_dpp(0, (int)hi, CTL, 0xf, 0xf, false); \
      u64 k2 = ((u64)hi2 << 32) | (u64)lo2; if (k2 > (K)) (K) = k2; }
#define RMAXF(V, CTL) { \
      float t_ = __int_as_float(__builtin_amdgcn_update_dpp(0, __float_as_int(V), CTL, 0xf, 0xf, false)); \
      (V) = fmaxf((V), t_); }
#define RMINU(V, CTL) { \
      u32 t_ = (u32)__builtin_amdgcn_update_dpp(0, (int)(V), CTL, 0xf, 0xf, false); \
      (V) = min((V), t_); }

  for (int k = 0; k < SS; ++k) {
    const int p = k & 1, pn = p ^ 1;
    // ---- cross-wave winner: reduce 16 keys (slots repeat every 16 lanes)
    u64 kk = sK[p][lane & 15];
    DPPK64(kk, 0x121) DPPK64(kk, 0x122) DPPK64(kk, 0x124) DPPK64(kk, 0x128)
    const u32 idx = 0xFFFFFFFFu - (u32)kk;
    if (tid == 0) fps_idx[b * SS + k] = (int)idx;
    // winner coords: same-address LDS broadcast (free)
    const float cx = lx[idx], cy = ly[idx], cz = lz[idx];

    // ---- own coords from LDS (lane-contiguous b128, conflict-free)
    const float4 Xa = ((const float4*)lx)[fbase], Xb = ((const float4*)lx)[fbase + 1024];
    const float4 Ya = ((const float4*)ly)[fbase], Yb = ((const float4*)ly)[fbase + 1024];
    const float4 Za = ((const float4*)lz)[fbase], Zb = ((const float4*)lz)[fbase + 1024];

    // ---- squared-distance update (bitwise np: materialized squares, (t0+t1)+t2)
#define UPDC(XX, YY, ZZ, DD) { \
      float dx_ = (XX) - cx, dy_ = (YY) - cy, dz_ = (ZZ) - cz; \
      float t0_ = dx_ * dx_, t1_ = dy_ * dy_, t2_ = dz_ * dz_; \
      float s_ = (t0_ + t1_) + t2_; \
      (DD) = fminf((DD), s_); }
    UPDC(Xa.x, Ya.x, Za.x, D0.x) UPDC(Xa.y, Ya.y, Za.y, D0.y)
    UPDC(Xa.z, Ya.z, Za.z, D0.z) UPDC(Xa.w, Ya.w, Za.w, D0.w)
    UPDC(Xb.x, Yb.x, Zb.x, D1.x) UPDC(Xb.y, Yb.y, Zb.y, D1.y)
    UPDC(Xb.z, Yb.z, Zb.z, D1.z) UPDC(Xb.w, Yb.w, Zb.w, D1.w)
#undef UPDC

    // ---- per-lane max of squared dists, one correctly-rounded sqrt
    float m2 = fmaxf(fmaxf(fmaxf(D0.x, D0.y), fmaxf(D0.z, D0.w)),
                     fmaxf(fmaxf(D1.x, D1.y), fmaxf(D1.z, D1.w)));
    float s = sqrtf(m2);

    // ---- wave max of s
    float sm = s;
    RMAXF(sm, 0x121) RMAXF(sm, 0x122) RMAXF(sm, 0x124) RMAXF(sm, 0x128)
    sm = fmaxf(sm, __shfl_xor(sm, 16, 64));
    sm = fmaxf(sm, __shfl_xor(sm, 32, 64));

    // ---- tied lanes: exact f64 preimage floor of sm's rounding interval,
    //      then first (smallest-global-index) point with D2 >= Lf
    u32 enc = 0xFFFFFFFFu;
    if (s == sm) {
      u32 sbits = __float_as_uint(sm);
      float spred = __uint_as_float(sbits - 1u);
      double M = ((double)spred + (double)sm) * 0.5;
      double L = M * M;
      if (sbits & 1u) L = __longlong_as_double(__double_as_longlong(L) + 1ll);
      float Lf = (float)L;
      if ((double)Lf < L) Lf = __uint_as_float(__float_as_uint(Lf) + 1u);
      int off = 4096 + 3;          // descending cascade -> smallest offset wins
      if (D1.z >= Lf) off = 4096 + 2;
      if (D1.y >= Lf) off = 4096 + 1;
      if (D1.x >= Lf) off = 4096 + 0;
      if (D0.w >= Lf) off = 3;
      if (D0.z >= Lf) off = 2;
      if (D0.y >= Lf) off = 1;
      if (D0.x >= Lf) off = 0;
      enc = ibase + (u32)off;      // global point index
    }
    RMINU(enc, 0x121) RMINU(enc, 0x122) RMINU(enc, 0x124) RMINU(enc, 0x128)
    enc = min(enc, (u32)__shfl_xor((int)enc, 16, 64));
    enc = min(enc, (u32)__shfl_xor((int)enc, 32, 64));

    if (lane == 0)
      sK[pn][wid] = (((u64)__float_as_uint(sm)) << 32) | (u64)(0xFFFFFFFFu - enc);
    __syncthreads();  // single barrier per step (double-buffered keys)
  }
#undef DPPK64
#undef RMAXF
#undef RMINU
}

// ---------------------------------------------------------------- gather new_coor + out0
__global__ void k_gather(const float* __restrict__ pc, const int* __restrict__ fps_idx,
                         float* __restrict__ ncoor, float* __restrict__ out0) {
  int t = blockIdx.x * 256 + threadIdx.x;
  if (t >= BB * SS) return;
  int b = t / SS, s = t % SS;
  int id = fps_idx[t];
  const float* base = pc + (size_t)b * 3 * NN;
  float x = base[id], y = base[NN + id], z = base[2 * NN + id];
  ncoor[(size_t)t * 3] = x; ncoor[(size_t)t * 3 + 1] = y; ncoor[(size_t)t * 3 + 2] = z;
  size_t o = (size_t)b * 3 * SS + s;
  out0[o] = x; out0[o + SS] = y; out0[o + 2 * SS] = z;
}

// ---------------------------------------------------------------- kNN (k=32 within radius, fill with argmin)
// Distance replicates np's _sqdist bit-for-bit:
//   dot: np.einsum inner sum-of-products loop -> gcc -ffp-contract=fast -> FMA chain
//        acc = fma(a2,b2, fma(a1,b1, a0*b0))
//   norms: np.sum(x**2,-1) over a MATERIALIZED squares array -> pure sequential adds (no FMA)
//   d = ((-2*dot) + ||q||^2) + ||p||^2  (sequential adds, f32 throughout)
__global__ __launch_bounds__(256) void k_knn(const float* __restrict__ candp,
                                             const float* __restrict__ newc,
                                             int mode, int ncand, float r2,
                                             int* __restrict__ gidx) {
  __shared__ float cd[2048];
  __shared__ int ci[2048];
  __shared__ int hist[64];
  __shared__ int cnt, oc, binT, mlow;
  const int q = blockIdx.x, tid = threadIdx.x;
  const int b = q / SS;
  if (tid == 0) { cnt = 0; oc = 0; }
  if (tid < 64) hist[tid] = 0;
  __syncthreads();
  const float qx = newc[(size_t)q * 3], qy = newc[(size_t)q * 3 + 1], qz = newc[(size_t)q * 3 + 2];
  float qn;
  {
#pragma clang fp contract(off)
    qn = (qx * qx + qy * qy) + qz * qz;
  }
  const float sc = 64.0f / r2;
  const float* base = (mode == 0) ? candp + (size_t)b * 3 * NN : candp + (size_t)b * SS * 3;
  for (int i = tid; i < ncand; i += 256) {
    float x, y, z;
    if (mode == 0) { x = base[i]; y = base[NN + i]; z = base[2 * NN + i]; }
    else { x = base[3 * i]; y = base[3 * i + 1]; z = base[3 * i + 2]; }
    // FMA-chain dot (np einsum), contract-off norms (np materialized squares)
    float dot = fmaf(qz, z, fmaf(qy, y, qx * x));
    float d;
    {
#pragma clang fp contract(off)
      float pn = (x * x + y * y) + z * z;
      d = ((-2.0f * dot) + qn) + pn;
    }
    if (d <= r2) {
      int pp = atomicAdd(&cnt, 1);
      if (pp < 2048) { cd[pp] = d; ci[pp] = i; }
      float db = (d > 0.0f) ? d : 0.0f;
      atomicAdd(&hist[min(63, (int)(db * sc))], 1);
    }
  }
  __syncthreads();
  const int M = min(cnt, 2048);
  if (tid == 0) {
    if (M > 32) {
      int c = 0, t = 0;
      for (t = 0; t < 64; ++t) { if (c + hist[t] >= 32) break; c += hist[t]; }
      binT = t; mlow = c;
    } else binT = -1;
  }
  __syncthreads();
  int* out = gidx + (size_t)q * 32;
  if (binT < 0) {
    for (int j = tid; j < M; j += 256) out[atomicAdd(&oc, 1)] = ci[j];
    __syncthreads();
    if (tid == 0 && M < 32) {
      float bd = 1e30f; int bx = 0x7FFFFFFF;
      for (int j = 0; j < M; ++j)
        if (cd[j] < bd || (cd[j] == bd && ci[j] < bx)) { bd = cd[j]; bx = ci[j]; }
      for (int j = M; j < 32; ++j) out[j] = bx;
    }
  } else {
    const int bt = binT, m = mlow;
    for (int j = tid; j < M; j += 256) {
      float dbj = (cd[j] > 0.0f) ? cd[j] : 0.0f;
      int bin = min(63, (int)(dbj * sc));
      if (bin < bt) out[atomicAdd(&oc, 1)] = ci[j];
      else if (bin == bt) {
        int r = 0; const float dj = cd[j]; const int ij = ci[j];
        for (int kk = 0; kk < M; ++kk) {
          float dbk = (cd[kk] > 0.0f) ? cd[kk] : 0.0f;
          if (min(63, (int)(dbk * sc)) == bt &&
              (cd[kk] < dj || (cd[kk] == dj && ci[kk] < ij))) ++r;
        }
        if (m + r < 32) out[m + r] = ci[j];
      }
    }
  }
}

// ---------------------------------------------------------------- grouped MLP + max  (out 128 ch)
template <int FDIM>
__global__ __launch_bounds__(256) void k_group_mlp(
    const float* __restrict__ fea, const int* __restrict__ gidx,
    const float* __restrict__ newc, const float* __restrict__ candp,
    int mode, int ncand, float radius,
    const float* __restrict__ wp, float* __restrict__ outf) {
  constexpr int CP4 = FDIM + 4;     // padded cols (67->68, 131->132)
  constexpr int NC4 = CP4 / 4;
  __shared__ float4 g4[2][32][NC4];
  __shared__ int sidx[2][32];
  __shared__ float sq[2][3];
  __shared__ float pf[2][4][128];
  const int tid = threadIdx.x;
  const int rs = tid >> 7, tl = tid & 127;
  const int dt = tl & 31, et = tl >> 5;
  const int d0 = dt * 4, e0 = et * 8;
  const int row0 = blockIdx.x * 16;
  for (int rp = 0; rp < 16; rp += 2) {
    const int row = row0 + rp + rs;
    if (tl < 32) sidx[rs][tl] = gidx[(size_t)row * 32 + tl];
    if (tl < 3) sq[rs][tl] = newc[(size_t)row * 3 + tl];
    __syncthreads();
    const int bb2 = row / SS;
    const float* fb = fea + (size_t)bb2 * ncand * FDIM;
    const float* cb = (mode == 0) ? candp + (size_t)bb2 * 3 * NN
                                  : candp + (size_t)bb2 * SS * 3;
    float* gf = (float*)&g4[rs][0][0];
    for (int qq = tl; qq < 32 * CP4; qq += 128) {
      int e = qq / CP4, c = qq - e * CP4;
      int id = sidx[rs][e];
      float v;
      if (c < FDIM) v = fb[(size_t)id * FDIM + c];
      else if (c < FDIM + 3) {
        int comp = c - FDIM;
        float pcv = (mode == 0) ? cb[(size_t)comp * NN + id] : cb[(size_t)id * 3 + comp];
        v = (pcv - sq[rs][comp]) / radius;
      } else v = 0.0f;
      gf[qq] = v;
    }
    __syncthreads();
    float acc[4][8];
#pragma unroll
    for (int i = 0; i < 4; ++i)
#pragma unroll
      for (int j = 0; j < 8; ++j) acc[i][j] = 0.0f;
    const float4* w4 = (const float4*)wp;
    for (int c4 = 0; c4 < NC4; ++c4) {
      float4 wv[4], gv[8];
#pragma unroll
      for (int i = 0; i < 4; ++i) wv[i] = w4[(size_t)(d0 + i) * NC4 + c4];
#pragma unroll
      for (int j = 0; j < 8; ++j) gv[j] = g4[rs][e0 + j][c4];
#pragma unroll
      for (int i = 0; i < 4; ++i)
#pragma unroll
        for (int j = 0; j < 8; ++j) {
          acc[i][j] += wv[i].x * gv[j].x;
          acc[i][j] += wv[i].y * gv[j].y;
          acc[i][j] += wv[i].z * gv[j].z;
          acc[i][j] += wv[i].w * gv[j].w;
        }
    }
#pragma unroll
    for (int i = 0; i < 4; ++i) {
      float m = acc[i][0];
#pragma unroll
      for (int j = 1; j < 8; ++j) m = fmaxf(m, acc[i][j]);
      pf[rs][et][d0 + i] = m;
    }
    __syncthreads();
    {
      const int d = tid & 127, r2s = tid >> 7;
      const int rowW = row0 + rp + r2s;
      float m = fmaxf(fmaxf(pf[r2s][0][d], pf[r2s][1][d]),
                      fmaxf(pf[r2s][2][d], pf[r2s][3][d]));
      outf[(size_t)rowW * 128 + d] = fmaxf(m, 0.0f);
    }
    __syncthreads();
  }
}

// ---------------------------------------------------------------- dense GEMM: Out = relu(A(M,K) * W(N,K)^T [+ Id])
template <bool RESID>
__global__ __launch_bounds__(256) void k_dense(
    const float* __restrict__ A, const float* __restrict__ W,
    const float* __restrict__ Id, float* __restrict__ Out,
    int K, int Ntot) {
  __shared__ float4 sa[64][17], sb[64][17];
  const int m0 = blockIdx.x * 64, n0 = blockIdx.y * 64;
  const int tid = threadIdx.x;
  const int mt = tid & 15, nt = tid >> 4;
  float acc[4][4];
#pragma unroll
  for (int i = 0; i < 4; ++i)
#pragma unroll
    for (int j = 0; j < 4; ++j) acc[i][j] = 0.0f;
  for (int kc = 0; kc < K; kc += 64) {
    for (int q2 = tid; q2 < 2048; q2 += 256) {
      int half = q2 >> 10, qq = q2 & 1023;
      int r = qq >> 4, c = qq & 15;
      const float* src = half ? (W + (size_t)(n0 + r) * K + kc + c * 4)
                              : (A + (size_t)(m0 + r) * K + kc + c * 4);
      float4 v = *(const float4*)src;
      if (half) sb[r][c] = v; else sa[r][c] = v;
    }
    __syncthreads();
#pragma unroll
    for (int c = 0; c < 16; ++c) {
      const int ks = (c + mt + nt) & 15;  // swizzle to break LDS bank conflicts
      float4 av[4], bv[4];
#pragma unroll
      for (int i = 0; i < 4; ++i) av[i] = sa[mt * 4 + i][ks];
#pragma unroll
      for (int j = 0; j < 4; ++j) bv[j] = sb[nt * 4 + j][ks];
#pragma unroll
      for (int i = 0; i < 4; ++i)
#pragma unroll
        for (int j = 0; j < 4; ++j) {
          acc[i][j] += av[i].x * bv[j].x;
          acc[i][j] += av[i].y * bv[j].y;
          acc[i][j] += av[i].z * bv[j].z;
          acc[i][j] += av[i].w * bv[j].w;
        }
    }
    __syncthreads();
  }
#pragma unroll
  for (int i = 0; i < 4; ++i)
#pragma unroll
    for (int j = 0; j < 4; ++j) {
      size_t o = (size_t)(m0 + mt * 4 + i) * Ntot + n0 + nt * 4 + j;
      float v = acc[i][j];
      if (RESID) v += Id[o];
      Out[o] = fmaxf(v, 0.0f);
    }
}

// ---------------------------------------------------------------- pad weights rows to 4-aligned cols
__global__ void k_pad_w(const float* __restrict__ src, float* __restrict__ dst,
                        int rows, int cin, int cp4) {
  int t = blockIdx.x * 256 + threadIdx.x;
  if (t >= rows * cp4) return;
  int r = t / cp4, c = t - r * cp4;
  dst[t] = (c < cin) ? src[(size_t)r * cin + c] : 0.0f;
}

// ---------------------------------------------------------------- out1 transpose (B*S,128) -> (B,128,S)
__global__ void k_out1_t(const float* __restrict__ in, float* __restrict__ out) {
  __shared__ float tile[32][33];
  const int b = blockIdx.z;
  const int s0 = blockIdx.x * 32, d0 = blockIdx.y * 32;
  const int tx = threadIdx.x, ty = threadIdx.y;
#pragma unroll
  for (int i = 0; i < 32; i += 8)
    tile[ty + i][tx] = in[(size_t)(b * SS + s0 + ty + i) * 128 + d0 + tx];
  __syncthreads();
#pragma unroll
  for (int i = 0; i < 32; i += 8)
    out[(size_t)(b * 128 + d0 + ty + i) * SS + s0 + tx] = tile[tx][ty + i];
}

// ----------------------------------------------------------------
extern "C" void kernel_launch(void* const* d_in, const int* in_sizes, int n_in,
                              void* d_out, int out_size, void* d_ws, size_t ws_size,
                              hipStream_t stream) {
  const float* pc    = (const float*)d_in[0];
  const float* pfea  = (const float*)d_in[1];
  const float* w_sa  = (const float*)d_in[2];
  const float* w_la1 = (const float*)d_in[3];
  const float* w1_1  = (const float*)d_in[4];
  const float* w2_1  = (const float*)d_in[5];
  const float* w_la2 = (const float*)d_in[6];
  const float* w1_2  = (const float*)d_in[7];
  const float* w2_2  = (const float*)d_in[8];
  float* out0 = (float*)d_out;
  float* out1 = out0 + (size_t)BB * 3 * SS;

  char* wsp = (char*)d_ws;
  size_t off = 0;
  auto alloc = [&](size_t bytes) -> void* {
    void* p = wsp + off;
    off = (off + bytes + 255) & ~(size_t)255;
    return p;
  };
  float* hbuf = (float*)alloc((size_t)BB * SS * HHV * 4);  // 16 MB; also aliased as feaT (disjoint in time)
  float* feaT = hbuf;                                      // 8 MB needed, used only before hbuf
  int*   fpsi = (int*)alloc((size_t)BB * SS * 4);
  float* ncoor = (float*)alloc((size_t)BB * SS * 3 * 4);
  int*   gi = (int*)alloc((size_t)BB * SS * GG * 4);
  float* fa = (float*)alloc((size_t)BB * SS * C2V * 4);
  float* fb = (float*)alloc((size_t)BB * SS * C2V * 4);
  float* wsap = (float*)alloc(128 * 68 * 4);
  float* wla1p = (float*)alloc(128 * 132 * 4);
  float* wla2p = (float*)alloc(128 * 132 * 4);

  k_pad_w<<<dim3((128 * 68 + 255) / 256), dim3(256), 0, stream>>>(w_sa, wsap, 128, 67, 68);
  k_pad_w<<<dim3((128 * 132 + 255) / 256), dim3(256), 0, stream>>>(w_la1, wla1p, 128, 131, 132);
  k_pad_w<<<dim3((128 * 132 + 255) / 256), dim3(256), 0, stream>>>(w_la2, wla2p, 128, 131, 132);

  k_transpose_fea<<<dim3(NN / 32, CC / 32, BB), dim3(32, 8), 0, stream>>>(pfea, feaT);
  k_fps<<<dim3(BB), dim3(1024), 0, stream>>>(pc, fpsi);
  k_gather<<<dim3((BB * SS + 255) / 256), dim3(256), 0, stream>>>(pc, fpsi, ncoor, out0);

  // stage 1: group among original N points, r=0.2
  k_knn<<<dim3(BB * SS), dim3(256), 0, stream>>>(pc, ncoor, 0, NN, 0.04f, gi);
  k_group_mlp<64><<<dim3(BB * SS / 16), dim3(256), 0, stream>>>(feaT, gi, ncoor, pc, 0, NN, 0.2f, wsap, fa);

  // shared grouping for both inv-res blocks (same points, same radius 0.4)
  k_knn<<<dim3(BB * SS), dim3(256), 0, stream>>>(ncoor, ncoor, 1, SS, 0.16f, gi);

  // inv-res block 1
  k_group_mlp<128><<<dim3(BB * SS / 16), dim3(256), 0, stream>>>(fa, gi, ncoor, ncoor, 1, SS, 0.4f, wla1p, fb);
  k_dense<false><<<dim3(128, 8), dim3(256), 0, stream>>>(fb, w1_1, nullptr, hbuf, 128, 512);
  k_dense<true><<<dim3(128, 2), dim3(256), 0, stream>>>(hbuf, w2_1, fa, fb, 512, 128);

  // inv-res block 2
  k_group_mlp<128><<<dim3(BB * SS / 16), dim3(256), 0, stream>>>(fb, gi, ncoor, ncoor, 1, SS, 0.4f, wla2p, fa);
  k_dense<false><<<dim3(128, 8), dim3(256), 0, stream>>>(fa, w1_2, nullptr, hbuf, 128, 512);
  k_dense<true><<<dim3(128, 2), dim3(256), 0, stream>>>(hbuf, w2_2, fb, fa, 512, 128);

  k_out1_t<<<dim3(SS / 32, 128 / 32, BB), dim3(32, 8), 0, stream>>>(fa, out1);
}

// Round 11
// 4283.112 us; speedup vs baseline: 1.1201x; 1.0019x over previous
//
#include <hip/hip_runtime.h>
#include <hip/hip_bf16.h>

#define BB 4
#define NN 8192
#define CC 64
#define SS 2048
#define GG 32
#define C2V 128
#define HHV 512

typedef unsigned long long u64;
typedef unsigned int u32;

// ---------------------------------------------------------------- transpose fea (B,C,N)->(B,N,C)
__global__ void k_transpose_fea(const float* __restrict__ in, float* __restrict__ out) {
  __shared__ float tile[32][33];
  const int b = blockIdx.z;
  const int n0 = blockIdx.x * 32, c0 = blockIdx.y * 32;
  const int tx = threadIdx.x, ty = threadIdx.y;
  const float* src = in + (size_t)b * CC * NN;
#pragma unroll
  for (int i = 0; i < 32; i += 8)
    tile[ty + i][tx] = src[(size_t)(c0 + ty + i) * NN + n0 + tx];
  __syncthreads();
  float* dst = out + (size_t)b * NN * CC;
#pragma unroll
  for (int i = 0; i < 32; i += 8)
    dst[(size_t)(n0 + ty + i) * CC + c0 + tx] = tile[tx][ty + i];
}

// ---------------------------------------------------------------- FPS (v6: LDS-staged coords)
// The r6-r9 register-residency fight is over: hipcc rematerializes loop-invariant
// global loads no matter what (VGPR stuck at 48-68, ~60% per-CU VALU on reload
// overhead). Deterministic fix: stage all 8192x3 coords in static LDS (96 KB of
// the 160 KB/CU). 1024 thr = 16 waves; each lane re-reads its 8 points per step
// via 6 conflict-free lane-contiguous ds_read_b128; only D^2 (8 floats) lives in
// registers. Winner coords = same-address broadcast LDS read at decoded idx.
// Ownership: lane owns points {c*4096 + wid*256 + lane*4 + e}; per-wave key
// (s_bits<<32 | ~global_idx) max-reduced via DPP gives exact np first-index
// argmax. Numerics = verified r5/r7-r9 chain: contract-off materialized squares,
// one correctly-rounded sqrtf per lane, exact f64 preimage floor of s's
// rounding interval for ties among sqrt-rounding-colliding points.
__global__ __launch_bounds__(1024, 4) void k_fps(const float* __restrict__ pc, int* __restrict__ fps_idx) {
#pragma clang fp contract(off)
  __shared__ float lx[NN], ly[NN], lz[NN];
  __shared__ u64 sK[2][16];
  const int b = blockIdx.x, tid = threadIdx.x;
  const int lane = tid & 63, wid = tid >> 6;
  const float* pb = pc + (size_t)b * 3 * NN;
  {
    const float4* gx = (const float4*)pb;
    const float4* gy = (const float4*)(pb + NN);
    const float4* gz = (const float4*)(pb + 2 * NN);
    float4* sx = (float4*)lx; float4* sy = (float4*)ly; float4* sz = (float4*)lz;
    sx[tid] = gx[tid]; sx[tid + 1024] = gx[tid + 1024];
    sy[tid] = gy[tid]; sy[tid + 1024] = gy[tid + 1024];
    sz[tid] = gz[tid]; sz[tid + 1024] = gz[tid + 1024];
  }
  if (tid < 32) ((u64*)sK)[tid] = 0ull;
  if (tid == 0) sK[0][0] = ~0ull;   // step-0 winner: idx 0 (s-bits all-ones beats any)
  __syncthreads();

  const int fbase = wid * 64 + lane;              // float4 index of chunk 0
  const u32 ibase = (u32)(wid * 256 + lane * 4);  // global point index base
  float4 D0 = make_float4(1e20f, 1e20f, 1e20f, 1e20f);
  float4 D1 = D0;

#define DPPK64(K, CTL) { \
      u32 lo = (u32)(K), hi = (u32)((K) >> 32); \
      u32 lo2 = (u32)__builtin_amdgcn_update_dpp(0, (int)lo, CTL, 0xf, 0xf, false); \
      u32 hi2 = (u32)__builtin_amdgcn_update_dpp(0, (int)hi, CTL, 0xf, 0xf, false); \
      u64 k2 = ((u64)hi2 << 32) | (u64)lo2; if (k2 > (K)) (K) = k2; }
#define RMAXF(V, CTL) { \
      float t_ = __int_as_float(__builtin_amdgcn_update_dpp(0, __float_as_int(V), CTL, 0xf, 0xf, false)); \
      (V) = fmaxf((V), t_); }
#define RMINU(V, CTL) { \
      u32 t_ = (u32)__builtin_amdgcn_update_dpp(0, (int)(V), CTL, 0xf, 0xf, false); \
      (V) = min((V), t_); }

  for (int k = 0; k < SS; ++k) {
    const int p = k & 1, pn = p ^ 1;
    // ---- cross-wave winner: reduce 16 keys (slots repeat every 16 lanes)
    u64 kk = sK[p][lane & 15];
    DPPK64(kk, 0x121) DPPK64(kk, 0x122) DPPK64(kk, 0x124) DPPK64(kk, 0x128)
    const u32 idx = 0xFFFFFFFFu - (u32)kk;
    if (tid == 0) fps_idx[b * SS + k] = (int)idx;
    // winner coords: same-address LDS broadcast (free)
    const float cx = lx[idx], cy = ly[idx], cz = lz[idx];

    // ---- own coords from LDS (lane-contiguous b128, conflict-free)
    const float4 Xa = ((const float4*)lx)[fbase], Xb = ((const float4*)lx)[fbase + 1024];
    const float4 Ya = ((const float4*)ly)[fbase], Yb = ((const float4*)ly)[fbase + 1024];
    const float4 Za = ((const float4*)lz)[fbase], Zb = ((const float4*)lz)[fbase + 1024];

    // ---- squared-distance update (bitwise np: materialized squares, (t0+t1)+t2)
#define UPDC(XX, YY, ZZ, DD) { \
      float dx_ = (XX) - cx, dy_ = (YY) - cy, dz_ = (ZZ) - cz; \
      float t0_ = dx_ * dx_, t1_ = dy_ * dy_, t2_ = dz_ * dz_; \
      float s_ = (t0_ + t1_) + t2_; \
      (DD) = fminf((DD), s_); }
    UPDC(Xa.x, Ya.x, Za.x, D0.x) UPDC(Xa.y, Ya.y, Za.y, D0.y)
    UPDC(Xa.z, Ya.z, Za.z, D0.z) UPDC(Xa.w, Ya.w, Za.w, D0.w)
    UPDC(Xb.x, Yb.x, Zb.x, D1.x) UPDC(Xb.y, Yb.y, Zb.y, D1.y)
    UPDC(Xb.z, Yb.z, Zb.z, D1.z) UPDC(Xb.w, Yb.w, Zb.w, D1.w)
#undef UPDC

    // ---- per-lane max of squared dists, one correctly-rounded sqrt
    float m2 = fmaxf(fmaxf(fmaxf(D0.x, D0.y), fmaxf(D0.z, D0.w)),
                     fmaxf(fmaxf(D1.x, D1.y), fmaxf(D1.z, D1.w)));
    float s = sqrtf(m2);

    // ---- wave max of s
    float sm = s;
    RMAXF(sm, 0x121) RMAXF(sm, 0x122) RMAXF(sm, 0x124) RMAXF(sm, 0x128)
    sm = fmaxf(sm, __shfl_xor(sm, 16, 64));
    sm = fmaxf(sm, __shfl_xor(sm, 32, 64));

    // ---- tied lanes: exact f64 preimage floor of sm's rounding interval,
    //      then first (smallest-global-index) point with D2 >= Lf
    u32 enc = 0xFFFFFFFFu;
    if (s == sm) {
      u32 sbits = __float_as_uint(sm);
      float spred = __uint_as_float(sbits - 1u);
      double M = ((double)spred + (double)sm) * 0.5;
      double L = M * M;
      if (sbits & 1u) L = __longlong_as_double(__double_as_longlong(L) + 1ll);
      float Lf = (float)L;
      if ((double)Lf < L) Lf = __uint_as_float(__float_as_uint(Lf) + 1u);
      int off = 4096 + 3;          // descending cascade -> smallest offset wins
      if (D1.z >= Lf) off = 4096 + 2;
      if (D1.y >= Lf) off = 4096 + 1;
      if (D1.x >= Lf) off = 4096 + 0;
      if (D0.w >= Lf) off = 3;
      if (D0.z >= Lf) off = 2;
      if (D0.y >= Lf) off = 1;
      if (D0.x >= Lf) off = 0;
      enc = ibase + (u32)off;      // global point index
    }
    RMINU(enc, 0x121) RMINU(enc, 0x122) RMINU(enc, 0x124) RMINU(enc, 0x128)
    enc = min(enc, (u32)__shfl_xor((int)enc, 16, 64));
    enc = min(enc, (u32)__shfl_xor((int)enc, 32, 64));

    if (lane == 0)
      sK[pn][wid] = (((u64)__float_as_uint(sm)) << 32) | (u64)(0xFFFFFFFFu - enc);
    __syncthreads();  // single barrier per step (double-buffered keys)
  }
#undef DPPK64
#undef RMAXF
#undef RMINU
}

// ---------------------------------------------------------------- gather new_coor + out0
__global__ void k_gather(const float* __restrict__ pc, const int* __restrict__ fps_idx,
                         float* __restrict__ ncoor, float* __restrict__ out0) {
  int t = blockIdx.x * 256 + threadIdx.x;
  if (t >= BB * SS) return;
  int b = t / SS, s = t % SS;
  int id = fps_idx[t];
  const float* base = pc + (size_t)b * 3 * NN;
  float x = base[id], y = base[NN + id], z = base[2 * NN + id];
  ncoor[(size_t)t * 3] = x; ncoor[(size_t)t * 3 + 1] = y; ncoor[(size_t)t * 3 + 2] = z;
  size_t o = (size_t)b * 3 * SS + s;
  out0[o] = x; out0[o + SS] = y; out0[o + 2 * SS] = z;
}

// ---------------------------------------------------------------- kNN (k=32 within radius, fill with argmin)
// Distance replicates np's _sqdist bit-for-bit:
//   dot: np.einsum inner sum-of-products loop -> gcc -ffp-contract=fast -> FMA chain
//        acc = fma(a2,b2, fma(a1,b1, a0*b0))
//   norms: np.sum(x**2,-1) over a MATERIALIZED squares array -> pure sequential adds (no FMA)
//   d = ((-2*dot) + ||q||^2) + ||p||^2  (sequential adds, f32 throughout)
__global__ __launch_bounds__(256) void k_knn(const float* __restrict__ candp,
                                             const float* __restrict__ newc,
                                             int mode, int ncand, float r2,
                                             int* __restrict__ gidx) {
  __shared__ float cd[2048];
  __shared__ int ci[2048];
  __shared__ int hist[64];
  __shared__ int cnt, oc, binT, mlow;
  const int q = blockIdx.x, tid = threadIdx.x;
  const int b = q / SS;
  if (tid == 0) { cnt = 0; oc = 0; }
  if (tid < 64) hist[tid] = 0;
  __syncthreads();
  const float qx = newc[(size_t)q * 3], qy = newc[(size_t)q * 3 + 1], qz = newc[(size_t)q * 3 + 2];
  float qn;
  {
#pragma clang fp contract(off)
    qn = (qx * qx + qy * qy) + qz * qz;
  }
  const float sc = 64.0f / r2;
  const float* base = (mode == 0) ? candp + (size_t)b * 3 * NN : candp + (size_t)b * SS * 3;
  for (int i = tid; i < ncand; i += 256) {
    float x, y, z;
    if (mode == 0) { x = base[i]; y = base[NN + i]; z = base[2 * NN + i]; }
    else { x = base[3 * i]; y = base[3 * i + 1]; z = base[3 * i + 2]; }
    // FMA-chain dot (np einsum), contract-off norms (np materialized squares)
    float dot = fmaf(qz, z, fmaf(qy, y, qx * x));
    float d;
    {
#pragma clang fp contract(off)
      float pn = (x * x + y * y) + z * z;
      d = ((-2.0f * dot) + qn) + pn;
    }
    if (d <= r2) {
      int pp = atomicAdd(&cnt, 1);
      if (pp < 2048) { cd[pp] = d; ci[pp] = i; }
      float db = (d > 0.0f) ? d : 0.0f;
      atomicAdd(&hist[min(63, (int)(db * sc))], 1);
    }
  }
  __syncthreads();
  const int M = min(cnt, 2048);
  if (tid == 0) {
    if (M > 32) {
      int c = 0, t = 0;
      for (t = 0; t < 64; ++t) { if (c + hist[t] >= 32) break; c += hist[t]; }
      binT = t; mlow = c;
    } else binT = -1;
  }
  __syncthreads();
  int* out = gidx + (size_t)q * 32;
  if (binT < 0) {
    for (int j = tid; j < M; j += 256) out[atomicAdd(&oc, 1)] = ci[j];
    __syncthreads();
    if (tid == 0 && M < 32) {
      float bd = 1e30f; int bx = 0x7FFFFFFF;
      for (int j = 0; j < M; ++j)
        if (cd[j] < bd || (cd[j] == bd && ci[j] < bx)) { bd = cd[j]; bx = ci[j]; }
      for (int j = M; j < 32; ++j) out[j] = bx;
    }
  } else {
    const int bt = binT, m = mlow;
    for (int j = tid; j < M; j += 256) {
      float dbj = (cd[j] > 0.0f) ? cd[j] : 0.0f;
      int bin = min(63, (int)(dbj * sc));
      if (bin < bt) out[atomicAdd(&oc, 1)] = ci[j];
      else if (bin == bt) {
        int r = 0; const float dj = cd[j]; const int ij = ci[j];
        for (int kk = 0; kk < M; ++kk) {
          float dbk = (cd[kk] > 0.0f) ? cd[kk] : 0.0f;
          if (min(63, (int)(dbk * sc)) == bt &&
              (cd[kk] < dj || (cd[kk] == dj && ci[kk] < ij))) ++r;
        }
        if (m + r < 32) out[m + r] = ci[j];
      }
    }
  }
}

// ---------------------------------------------------------------- grouped MLP + max  (out 128 ch)
template <int FDIM>
__global__ __launch_bounds__(256) void k_group_mlp(
    const float* __restrict__ fea, const int* __restrict__ gidx,
    const float* __restrict__ newc, const float* __restrict__ candp,
    int mode, int ncand, float radius,
    const float* __restrict__ wp, float* __restrict__ outf) {
  constexpr int CP4 = FDIM + 4;     // padded cols (67->68, 131->132)
  constexpr int NC4 = CP4 / 4;
  __shared__ float4 g4[2][32][NC4];
  __shared__ int sidx[2][32];
  __shared__ float sq[2][3];
  __shared__ float pf[2][4][128];
  const int tid = threadIdx.x;
  const int rs = tid >> 7, tl = tid & 127;
  const int dt = tl & 31, et = tl >> 5;
  const int d0 = dt * 4, e0 = et * 8;
  const int row0 = blockIdx.x * 16;
  for (int rp = 0; rp < 16; rp += 2) {
    const int row = row0 + rp + rs;
    if (tl < 32) sidx[rs][tl] = gidx[(size_t)row * 32 + tl];
    if (tl < 3) sq[rs][tl] = newc[(size_t)row * 3 + tl];
    __syncthreads();
    const int bb2 = row / SS;
    const float* fb = fea + (size_t)bb2 * ncand * FDIM;
    const float* cb = (mode == 0) ? candp + (size_t)bb2 * 3 * NN
                                  : candp + (size_t)bb2 * SS * 3;
    float* gf = (float*)&g4[rs][0][0];
    for (int qq = tl; qq < 32 * CP4; qq += 128) {
      int e = qq / CP4, c = qq - e * CP4;
      int id = sidx[rs][e];
      float v;
      if (c < FDIM) v = fb[(size_t)id * FDIM + c];
      else if (c < FDIM + 3) {
        int comp = c - FDIM;
        float pcv = (mode == 0) ? cb[(size_t)comp * NN + id] : cb[(size_t)id * 3 + comp];
        v = (pcv - sq[rs][comp]) / radius;
      } else v = 0.0f;
      gf[qq] = v;
    }
    __syncthreads();
    float acc[4][8];
#pragma unroll
    for (int i = 0; i < 4; ++i)
#pragma unroll
      for (int j = 0; j < 8; ++j) acc[i][j] = 0.0f;
    const float4* w4 = (const float4*)wp;
    for (int c4 = 0; c4 < NC4; ++c4) {
      float4 wv[4], gv[8];
#pragma unroll
      for (int i = 0; i < 4; ++i) wv[i] = w4[(size_t)(d0 + i) * NC4 + c4];
#pragma unroll
      for (int j = 0; j < 8; ++j) gv[j] = g4[rs][e0 + j][c4];
#pragma unroll
      for (int i = 0; i < 4; ++i)
#pragma unroll
        for (int j = 0; j < 8; ++j) {
          acc[i][j] += wv[i].x * gv[j].x;
          acc[i][j] += wv[i].y * gv[j].y;
          acc[i][j] += wv[i].z * gv[j].z;
          acc[i][j] += wv[i].w * gv[j].w;
        }
    }
#pragma unroll
    for (int i = 0; i < 4; ++i) {
      float m = acc[i][0];
#pragma unroll
      for (int j = 1; j < 8; ++j) m = fmaxf(m, acc[i][j]);
      pf[rs][et][d0 + i] = m;
    }
    __syncthreads();
    {
      const int d = tid & 127, r2s = tid >> 7;
      const int rowW = row0 + rp + r2s;
      float m = fmaxf(fmaxf(pf[r2s][0][d], pf[r2s][1][d]),
                      fmaxf(pf[r2s][2][d], pf[r2s][3][d]));
      outf[(size_t)rowW * 128 + d] = fmaxf(m, 0.0f);
    }
    __syncthreads();
  }
}

// ---------------------------------------------------------------- dense GEMM: Out = relu(A(M,K) * W(N,K)^T [+ Id])
template <bool RESID>
__global__ __launch_bounds__(256) void k_dense(
    const float* __restrict__ A, const float* __restrict__ W,
    const float* __restrict__ Id, float* __restrict__ Out,
    int K, int Ntot) {
  __shared__ float4 sa[64][17], sb[64][17];
  const int m0 = blockIdx.x * 64, n0 = blockIdx.y * 64;
  const int tid = threadIdx.x;
  const int mt = tid & 15, nt = tid >> 4;
  float acc[4][4];
#pragma unroll
  for (int i = 0; i < 4; ++i)
#pragma unroll
    for (int j = 0; j < 4; ++j) acc[i][j] = 0.0f;
  for (int kc = 0; kc < K; kc += 64) {
    for (int q2 = tid; q2 < 2048; q2 += 256) {
      int half = q2 >> 10, qq = q2 & 1023;
      int r = qq >> 4, c = qq & 15;
      const float* src = half ? (W + (size_t)(n0 + r) * K + kc + c * 4)
                              : (A + (size_t)(m0 + r) * K + kc + c * 4);
      float4 v = *(const float4*)src;
      if (half) sb[r][c] = v; else sa[r][c] = v;
    }
    __syncthreads();
#pragma unroll
    for (int c = 0; c < 16; ++c) {
      const int ks = (c + mt + nt) & 15;  // swizzle to break LDS bank conflicts
      float4 av[4], bv[4];
#pragma unroll
      for (int i = 0; i < 4; ++i) av[i] = sa[mt * 4 + i][ks];
#pragma unroll
      for (int j = 0; j < 4; ++j) bv[j] = sb[nt * 4 + j][ks];
#pragma unroll
      for (int i = 0; i < 4; ++i)
#pragma unroll
        for (int j = 0; j < 4; ++j) {
          acc[i][j] += av[i].x * bv[j].x;
          acc[i][j] += av[i].y * bv[j].y;
          acc[i][j] += av[i].z * bv[j].z;
          acc[i][j] += av[i].w * bv[j].w;
        }
    }
    __syncthreads();
  }
#pragma unroll
  for (int i = 0; i < 4; ++i)
#pragma unroll
    for (int j = 0; j < 4; ++j) {
      size_t o = (size_t)(m0 + mt * 4 + i) * Ntot + n0 + nt * 4 + j;
      float v = acc[i][j];
      if (RESID) v += Id[o];
      Out[o] = fmaxf(v, 0.0f);
    }
}

// ---------------------------------------------------------------- pad weights rows to 4-aligned cols
__global__ void k_pad_w(const float* __restrict__ src, float* __restrict__ dst,
                        int rows, int cin, int cp4) {
  int t = blockIdx.x * 256 + threadIdx.x;
  if (t >= rows * cp4) return;
  int r = t / cp4, c = t - r * cp4;
  dst[t] = (c < cin) ? src[(size_t)r * cin + c] : 0.0f;
}

// ---------------------------------------------------------------- out1 transpose (B*S,128) -> (B,128,S)
__global__ void k_out1_t(const float* __restrict__ in, float* __restrict__ out) {
  __shared__ float tile[32][33];
  const int b = blockIdx.z;
  const int s0 = blockIdx.x * 32, d0 = blockIdx.y * 32;
  const int tx = threadIdx.x, ty = threadIdx.y;
#pragma unroll
  for (int i = 0; i < 32; i += 8)
    tile[ty + i][tx] = in[(size_t)(b * SS + s0 + ty + i) * 128 + d0 + tx];
  __syncthreads();
#pragma unroll
  for (int i = 0; i < 32; i += 8)
    out[(size_t)(b * 128 + d0 + ty + i) * SS + s0 + tx] = tile[tx][ty + i];
}

// ----------------------------------------------------------------
extern "C" void kernel_launch(void* const* d_in, const int* in_sizes, int n_in,
                              void* d_out, int out_size, void* d_ws, size_t ws_size,
                              hipStream_t stream) {
  const float* pc    = (const float*)d_in[0];
  const float* pfea  = (const float*)d_in[1];
  const float* w_sa  = (const float*)d_in[2];
  const float* w_la1 = (const float*)d_in[3];
  const float* w1_1  = (const float*)d_in[4];
  const float* w2_1  = (const float*)d_in[5];
  const float* w_la2 = (const float*)d_in[6];
  const float* w1_2  = (const float*)d_in[7];
  const float* w2_2  = (const float*)d_in[8];
  float* out0 = (float*)d_out;
  float* out1 = out0 + (size_t)BB * 3 * SS;

  char* wsp = (char*)d_ws;
  size_t off = 0;
  auto alloc = [&](size_t bytes) -> void* {
    void* p = wsp + off;
    off = (off + bytes + 255) & ~(size_t)255;
    return p;
  };
  float* hbuf = (float*)alloc((size_t)BB * SS * HHV * 4);  // 16 MB; also aliased as feaT (disjoint in time)
  float* feaT = hbuf;                                      // 8 MB needed, used only before hbuf
  int*   fpsi = (int*)alloc((size_t)BB * SS * 4);
  float* ncoor = (float*)alloc((size_t)BB * SS * 3 * 4);
  int*   gi = (int*)alloc((size_t)BB * SS * GG * 4);
  float* fa = (float*)alloc((size_t)BB * SS * C2V * 4);
  float* fb = (float*)alloc((size_t)BB * SS * C2V * 4);
  float* wsap = (float*)alloc(128 * 68 * 4);
  float* wla1p = (float*)alloc(128 * 132 * 4);
  float* wla2p = (float*)alloc(128 * 132 * 4);

  k_pad_w<<<dim3((128 * 68 + 255) / 256), dim3(256), 0, stream>>>(w_sa, wsap, 128, 67, 68);
  k_pad_w<<<dim3((128 * 132 + 255) / 256), dim3(256), 0, stream>>>(w_la1, wla1p, 128, 131, 132);
  k_pad_w<<<dim3((128 * 132 + 255) / 256), dim3(256), 0, stream>>>(w_la2, wla2p, 128, 131, 132);

  k_transpose_fea<<<dim3(NN / 32, CC / 32, BB), dim3(32, 8), 0, stream>>>(pfea, feaT);
  k_fps<<<dim3(BB), dim3(1024), 0, stream>>>(pc, fpsi);
  k_gather<<<dim3((BB * SS + 255) / 256), dim3(256), 0, stream>>>(pc, fpsi, ncoor, out0);

  // stage 1: group among original N points, r=0.2
  k_knn<<<dim3(BB * SS), dim3(256), 0, stream>>>(pc, ncoor, 0, NN, 0.04f, gi);
  k_group_mlp<64><<<dim3(BB * SS / 16), dim3(256), 0, stream>>>(feaT, gi, ncoor, pc, 0, NN, 0.2f, wsap, fa);

  // shared grouping for both inv-res blocks (same points, same radius 0.4)
  k_knn<<<dim3(BB * SS), dim3(256), 0, stream>>>(ncoor, ncoor, 1, SS, 0.16f, gi);

  // inv-res block 1
  k_group_mlp<128><<<dim3(BB * SS / 16), dim3(256), 0, stream>>>(fa, gi, ncoor, ncoor, 1, SS, 0.4f, wla1p, fb);
  k_dense<false><<<dim3(128, 8), dim3(256), 0, stream>>>(fb, w1_1, nullptr, hbuf, 128, 512);
  k_dense<true><<<dim3(128, 2), dim3(256), 0, stream>>>(hbuf, w2_1, fa, fb, 512, 128);

  // inv-res block 2
  k_group_mlp<128><<<dim3(BB * SS / 16), dim3(256), 0, stream>>>(fb, gi, ncoor, ncoor, 1, SS, 0.4f, wla2p, fa);
  k_dense<false><<<dim3(128, 8), dim3(256), 0, stream>>>(fa, w1_2, nullptr, hbuf, 128, 512);
  k_dense<true><<<dim3(128, 2), dim3(256), 0, stream>>>(hbuf, w2_2, fb, fa, 512, 128);

  k_out1_t<<<dim3(SS / 32, 128 / 32, BB), dim3(32, 8), 0, stream>>>(fa, out1);
}

// Round 12
// 4281.473 us; speedup vs baseline: 1.1205x; 1.0004x over previous
//
#include <hip/hip_runtime.h>
#include <hip/hip_bf16.h>

#define BB 4
#define NN 8192
#define CC 64
#define SS 2048
#define GG 32
#define C2V 128
#define HHV 512

typedef unsigned long long u64;
typedef unsigned int u32;

// ---------------------------------------------------------------- transpose fea (B,C,N)->(B,N,C)
__global__ void k_transpose_fea(const float* __restrict__ in, float* __restrict__ out) {
  __shared__ float tile[32][33];
  const int b = blockIdx.z;
  const int n0 = blockIdx.x * 32, c0 = blockIdx.y * 32;
  const int tx = threadIdx.x, ty = threadIdx.y;
  const float* src = in + (size_t)b * CC * NN;
#pragma unroll
  for (int i = 0; i < 32; i += 8)
    tile[ty + i][tx] = src[(size_t)(c0 + ty + i) * NN + n0 + tx];
  __syncthreads();
  float* dst = out + (size_t)b * NN * CC;
#pragma unroll
  for (int i = 0; i < 32; i += 8)
    dst[(size_t)(n0 + ty + i) * CC + c0 + tx] = tile[tx][ty + i];
}

// ---------------------------------------------------------------- FPS (v7)
// LDS-staged coords (96 KB) + LDS-buffered output indices (8 KB): NO global
// memory ops inside the 2048-step loop -> __syncthreads drains lgkmcnt only.
// Per step: key ds_read issued FIRST, then the 6 own-coord ds_read_b128s
// (in-order lgkmcnt return => key completes while coords stream under the
// DPP reduce + broadcast-read latency). Wave max reduced on SQUARED dists;
// s = sqrtf(m2w) + exact f64 preimage floor Lf computed wave-uniformly (no
// divergent branch); first-index candidate = descending cascade D >= Lf;
// cross-lane/cross-wave min-index on (s_bits, ~idx) keys. Numerics = verified
// r5-r11 chain (contract-off materialized squares, correctly-rounded sqrt,
// exact preimage tie-break).
__global__ __launch_bounds__(1024, 4) void k_fps(const float* __restrict__ pc, int* __restrict__ fps_idx) {
#pragma clang fp contract(off)
  __shared__ float lx[NN], ly[NN], lz[NN];
  __shared__ int sIdx[SS];
  __shared__ u64 sK[2][16];
  const int b = blockIdx.x, tid = threadIdx.x;
  const int lane = tid & 63, wid = tid >> 6;
  const float* pb = pc + (size_t)b * 3 * NN;
  {
    const float4* gx = (const float4*)pb;
    const float4* gy = (const float4*)(pb + NN);
    const float4* gz = (const float4*)(pb + 2 * NN);
    float4* sx = (float4*)lx; float4* sy = (float4*)ly; float4* sz = (float4*)lz;
    sx[tid] = gx[tid]; sx[tid + 1024] = gx[tid + 1024];
    sy[tid] = gy[tid]; sy[tid + 1024] = gy[tid + 1024];
    sz[tid] = gz[tid]; sz[tid + 1024] = gz[tid + 1024];
  }
  if (tid < 32) ((u64*)sK)[tid] = 0ull;
  if (tid == 0) sK[0][0] = ~0ull;   // step-0 winner: idx 0
  __syncthreads();

  const int fbase = wid * 64 + lane;              // float4 index of chunk a
  const u32 ibase = (u32)(wid * 256 + lane * 4);  // global point index base
  float4 D0 = make_float4(1e20f, 1e20f, 1e20f, 1e20f);
  float4 D1 = D0;

#define DPPK64(K, CTL) { \
      u32 lo = (u32)(K), hi = (u32)((K) >> 32); \
      u32 lo2 = (u32)__builtin_amdgcn_update_dpp(0, (int)lo, CTL, 0xf, 0xf, false); \
      u32 hi2 = (u32)__builtin_amdgcn_update_dpp(0, (int)hi, CTL, 0xf, 0xf, false); \
      u64 k2 = ((u64)hi2 << 32) | (u64)lo2; if (k2 > (K)) (K) = k2; }
#define RMAXF(V, CTL) { \
      float t_ = __int_as_float(__builtin_amdgcn_update_dpp(0, __float_as_int(V), CTL, 0xf, 0xf, false)); \
      (V) = fmaxf((V), t_); }
#define RMINU(V, CTL) { \
      u32 t_ = (u32)__builtin_amdgcn_update_dpp(0, (int)(V), CTL, 0xf, 0xf, false); \
      (V) = min((V), t_); }

  for (int k = 0; k < SS; ++k) {
    const int p = k & 1, pn = p ^ 1;
    // ---- key read FIRST (completes first: in-order lgkmcnt), coords stream behind
    u64 kk = sK[p][lane & 15];
    const float4 Xa = ((const float4*)lx)[fbase], Xb = ((const float4*)lx)[fbase + 1024];
    const float4 Ya = ((const float4*)ly)[fbase], Yb = ((const float4*)ly)[fbase + 1024];
    const float4 Za = ((const float4*)lz)[fbase], Zb = ((const float4*)lz)[fbase + 1024];
    // ---- cross-wave winner (slots repeat every 16 lanes)
    DPPK64(kk, 0x121) DPPK64(kk, 0x122) DPPK64(kk, 0x124) DPPK64(kk, 0x128)
    const u32 idx = 0xFFFFFFFFu - (u32)kk;
    if (tid == 0) sIdx[k] = (int)idx;
    // winner coords: same-address LDS broadcast
    const float cx = lx[idx], cy = ly[idx], cz = lz[idx];

    // ---- squared-distance update (bitwise np: materialized squares, (t0+t1)+t2)
#define UPDC(XX, YY, ZZ, DD) { \
      float dx_ = (XX) - cx, dy_ = (YY) - cy, dz_ = (ZZ) - cz; \
      float t0_ = dx_ * dx_, t1_ = dy_ * dy_, t2_ = dz_ * dz_; \
      float s_ = (t0_ + t1_) + t2_; \
      (DD) = fminf((DD), s_); }
    UPDC(Xa.x, Ya.x, Za.x, D0.x) UPDC(Xa.y, Ya.y, Za.y, D0.y)
    UPDC(Xa.z, Ya.z, Za.z, D0.z) UPDC(Xa.w, Ya.w, Za.w, D0.w)
    UPDC(Xb.x, Yb.x, Zb.x, D1.x) UPDC(Xb.y, Yb.y, Zb.y, D1.y)
    UPDC(Xb.z, Yb.z, Zb.z, D1.z) UPDC(Xb.w, Yb.w, Zb.w, D1.w)
#undef UPDC

    // ---- per-lane max of squared dists, wave butterfly on m2 (sqrt-free)
    float m2 = fmaxf(fmaxf(fmaxf(D0.x, D0.y), fmaxf(D0.z, D0.w)),
                     fmaxf(fmaxf(D1.x, D1.y), fmaxf(D1.z, D1.w)));
    RMAXF(m2, 0x121) RMAXF(m2, 0x122) RMAXF(m2, 0x124) RMAXF(m2, 0x128)
    m2 = fmaxf(m2, __shfl_xor(m2, 16, 64));
    m2 = fmaxf(m2, __shfl_xor(m2, 32, 64));   // m2 = wave max (uniform)

    // ---- wave-uniform: s = fl(sqrt(m2w)), exact f64 preimage floor Lf of s's
    //      rounding interval; {D : fl(sqrt(D)) == s} == {D : D >= Lf}
    float s = sqrtf(m2);
    u32 sbits = __float_as_uint(s);
    float spred = __uint_as_float(sbits - 1u);
    double M = ((double)spred + (double)s) * 0.5;
    double L = M * M;
    if (sbits & 1u) L = __longlong_as_double(__double_as_longlong(L) + 1ll);
    float Lf = (float)L;
    if ((double)Lf < L) Lf = __uint_as_float(__float_as_uint(Lf) + 1u);

    // ---- first (smallest global index) candidate per lane: descending cascade
    u32 enc = 0xFFFFFFFFu;
    {
      int off = -1;
      if (D1.w >= Lf) off = 4096 + 3;
      if (D1.z >= Lf) off = 4096 + 2;
      if (D1.y >= Lf) off = 4096 + 1;
      if (D1.x >= Lf) off = 4096 + 0;
      if (D0.w >= Lf) off = 3;
      if (D0.z >= Lf) off = 2;
      if (D0.y >= Lf) off = 1;
      if (D0.x >= Lf) off = 0;
      if (off >= 0) enc = ibase + (u32)off;
    }
    RMINU(enc, 0x121) RMINU(enc, 0x122) RMINU(enc, 0x124) RMINU(enc, 0x128)
    enc = min(enc, (u32)__shfl_xor((int)enc, 16, 64));
    enc = min(enc, (u32)__shfl_xor((int)enc, 32, 64));

    if (lane == 0)
      sK[pn][wid] = (((u64)sbits) << 32) | (u64)(0xFFFFFFFFu - enc);
    __syncthreads();  // single barrier per step; lgkmcnt-only drain (no vmem in loop)
  }
#undef DPPK64
#undef RMAXF
#undef RMINU
  // bulk writeout (coalesced)
  fps_idx[b * SS + tid] = sIdx[tid];
  fps_idx[b * SS + 1024 + tid] = sIdx[1024 + tid];
}

// ---------------------------------------------------------------- gather new_coor + out0
__global__ void k_gather(const float* __restrict__ pc, const int* __restrict__ fps_idx,
                         float* __restrict__ ncoor, float* __restrict__ out0) {
  int t = blockIdx.x * 256 + threadIdx.x;
  if (t >= BB * SS) return;
  int b = t / SS, s = t % SS;
  int id = fps_idx[t];
  const float* base = pc + (size_t)b * 3 * NN;
  float x = base[id], y = base[NN + id], z = base[2 * NN + id];
  ncoor[(size_t)t * 3] = x; ncoor[(size_t)t * 3 + 1] = y; ncoor[(size_t)t * 3 + 2] = z;
  size_t o = (size_t)b * 3 * SS + s;
  out0[o] = x; out0[o + SS] = y; out0[o + 2 * SS] = z;
}

// ---------------------------------------------------------------- kNN (k=32 within radius, fill with argmin)
// Distance replicates np's _sqdist bit-for-bit:
//   dot: np.einsum inner sum-of-products loop -> gcc -ffp-contract=fast -> FMA chain
//        acc = fma(a2,b2, fma(a1,b1, a0*b0))
//   norms: np.sum(x**2,-1) over a MATERIALIZED squares array -> pure sequential adds (no FMA)
//   d = ((-2*dot) + ||q||^2) + ||p||^2  (sequential adds, f32 throughout)
__global__ __launch_bounds__(256) void k_knn(const float* __restrict__ candp,
                                             const float* __restrict__ newc,
                                             int mode, int ncand, float r2,
                                             int* __restrict__ gidx) {
  __shared__ float cd[2048];
  __shared__ int ci[2048];
  __shared__ int hist[64];
  __shared__ int cnt, oc, binT, mlow;
  const int q = blockIdx.x, tid = threadIdx.x;
  const int b = q / SS;
  if (tid == 0) { cnt = 0; oc = 0; }
  if (tid < 64) hist[tid] = 0;
  __syncthreads();
  const float qx = newc[(size_t)q * 3], qy = newc[(size_t)q * 3 + 1], qz = newc[(size_t)q * 3 + 2];
  float qn;
  {
#pragma clang fp contract(off)
    qn = (qx * qx + qy * qy) + qz * qz;
  }
  const float sc = 64.0f / r2;
  const float* base = (mode == 0) ? candp + (size_t)b * 3 * NN : candp + (size_t)b * SS * 3;
  for (int i = tid; i < ncand; i += 256) {
    float x, y, z;
    if (mode == 0) { x = base[i]; y = base[NN + i]; z = base[2 * NN + i]; }
    else { x = base[3 * i]; y = base[3 * i + 1]; z = base[3 * i + 2]; }
    // FMA-chain dot (np einsum), contract-off norms (np materialized squares)
    float dot = fmaf(qz, z, fmaf(qy, y, qx * x));
    float d;
    {
#pragma clang fp contract(off)
      float pn = (x * x + y * y) + z * z;
      d = ((-2.0f * dot) + qn) + pn;
    }
    if (d <= r2) {
      int pp = atomicAdd(&cnt, 1);
      if (pp < 2048) { cd[pp] = d; ci[pp] = i; }
      float db = (d > 0.0f) ? d : 0.0f;
      atomicAdd(&hist[min(63, (int)(db * sc))], 1);
    }
  }
  __syncthreads();
  const int M = min(cnt, 2048);
  if (tid == 0) {
    if (M > 32) {
      int c = 0, t = 0;
      for (t = 0; t < 64; ++t) { if (c + hist[t] >= 32) break; c += hist[t]; }
      binT = t; mlow = c;
    } else binT = -1;
  }
  __syncthreads();
  int* out = gidx + (size_t)q * 32;
  if (binT < 0) {
    for (int j = tid; j < M; j += 256) out[atomicAdd(&oc, 1)] = ci[j];
    __syncthreads();
    if (tid == 0 && M < 32) {
      float bd = 1e30f; int bx = 0x7FFFFFFF;
      for (int j = 0; j < M; ++j)
        if (cd[j] < bd || (cd[j] == bd && ci[j] < bx)) { bd = cd[j]; bx = ci[j]; }
      for (int j = M; j < 32; ++j) out[j] = bx;
    }
  } else {
    const int bt = binT, m = mlow;
    for (int j = tid; j < M; j += 256) {
      float dbj = (cd[j] > 0.0f) ? cd[j] : 0.0f;
      int bin = min(63, (int)(dbj * sc));
      if (bin < bt) out[atomicAdd(&oc, 1)] = ci[j];
      else if (bin == bt) {
        int r = 0; const float dj = cd[j]; const int ij = ci[j];
        for (int kk = 0; kk < M; ++kk) {
          float dbk = (cd[kk] > 0.0f) ? cd[kk] : 0.0f;
          if (min(63, (int)(dbk * sc)) == bt &&
              (cd[kk] < dj || (cd[kk] == dj && ci[kk] < ij))) ++r;
        }
        if (m + r < 32) out[m + r] = ci[j];
      }
    }
  }
}

// ---------------------------------------------------------------- grouped MLP + max  (out 128 ch)
template <int FDIM>
__global__ __launch_bounds__(256) void k_group_mlp(
    const float* __restrict__ fea, const int* __restrict__ gidx,
    const float* __restrict__ newc, const float* __restrict__ candp,
    int mode, int ncand, float radius,
    const float* __restrict__ wp, float* __restrict__ outf) {
  constexpr int CP4 = FDIM + 4;     // padded cols (67->68, 131->132)
  constexpr int NC4 = CP4 / 4;
  __shared__ float4 g4[2][32][NC4];
  __shared__ int sidx[2][32];
  __shared__ float sq[2][3];
  __shared__ float pf[2][4][128];
  const int tid = threadIdx.x;
  const int rs = tid >> 7, tl = tid & 127;
  const int dt = tl & 31, et = tl >> 5;
  const int d0 = dt * 4, e0 = et * 8;
  const int row0 = blockIdx.x * 16;
  for (int rp = 0; rp < 16; rp += 2) {
    const int row = row0 + rp + rs;
    if (tl < 32) sidx[rs][tl] = gidx[(size_t)row * 32 + tl];
    if (tl < 3) sq[rs][tl] = newc[(size_t)row * 3 + tl];
    __syncthreads();
    const int bb2 = row / SS;
    const float* fb = fea + (size_t)bb2 * ncand * FDIM;
    const float* cb = (mode == 0) ? candp + (size_t)bb2 * 3 * NN
                                  : candp + (size_t)bb2 * SS * 3;
    float* gf = (float*)&g4[rs][0][0];
    for (int qq = tl; qq < 32 * CP4; qq += 128) {
      int e = qq / CP4, c = qq - e * CP4;
      int id = sidx[rs][e];
      float v;
      if (c < FDIM) v = fb[(size_t)id * FDIM + c];
      else if (c < FDIM + 3) {
        int comp = c - FDIM;
        float pcv = (mode == 0) ? cb[(size_t)comp * NN + id] : cb[(size_t)id * 3 + comp];
        v = (pcv - sq[rs][comp]) / radius;
      } else v = 0.0f;
      gf[qq] = v;
    }
    __syncthreads();
    float acc[4][8];
#pragma unroll
    for (int i = 0; i < 4; ++i)
#pragma unroll
      for (int j = 0; j < 8; ++j) acc[i][j] = 0.0f;
    const float4* w4 = (const float4*)wp;
    for (int c4 = 0; c4 < NC4; ++c4) {
      float4 wv[4], gv[8];
#pragma unroll
      for (int i = 0; i < 4; ++i) wv[i] = w4[(size_t)(d0 + i) * NC4 + c4];
#pragma unroll
      for (int j = 0; j < 8; ++j) gv[j] = g4[rs][e0 + j][c4];
#pragma unroll
      for (int i = 0; i < 4; ++i)
#pragma unroll
        for (int j = 0; j < 8; ++j) {
          acc[i][j] += wv[i].x * gv[j].x;
          acc[i][j] += wv[i].y * gv[j].y;
          acc[i][j] += wv[i].z * gv[j].z;
          acc[i][j] += wv[i].w * gv[j].w;
        }
    }
#pragma unroll
    for (int i = 0; i < 4; ++i) {
      float m = acc[i][0];
#pragma unroll
      for (int j = 1; j < 8; ++j) m = fmaxf(m, acc[i][j]);
      pf[rs][et][d0 + i] = m;
    }
    __syncthreads();
    {
      const int d = tid & 127, r2s = tid >> 7;
      const int rowW = row0 + rp + r2s;
      float m = fmaxf(fmaxf(pf[r2s][0][d], pf[r2s][1][d]),
                      fmaxf(pf[r2s][2][d], pf[r2s][3][d]));
      outf[(size_t)rowW * 128 + d] = fmaxf(m, 0.0f);
    }
    __syncthreads();
  }
}

// ---------------------------------------------------------------- dense GEMM: Out = relu(A(M,K) * W(N,K)^T [+ Id])
template <bool RESID>
__global__ __launch_bounds__(256) void k_dense(
    const float* __restrict__ A, const float* __restrict__ W,
    const float* __restrict__ Id, float* __restrict__ Out,
    int K, int Ntot) {
  __shared__ float4 sa[64][17], sb[64][17];
  const int m0 = blockIdx.x * 64, n0 = blockIdx.y * 64;
  const int tid = threadIdx.x;
  const int mt = tid & 15, nt = tid >> 4;
  float acc[4][4];
#pragma unroll
  for (int i = 0; i < 4; ++i)
#pragma unroll
    for (int j = 0; j < 4; ++j) acc[i][j] = 0.0f;
  for (int kc = 0; kc < K; kc += 64) {
    for (int q2 = tid; q2 < 2048; q2 += 256) {
      int half = q2 >> 10, qq = q2 & 1023;
      int r = qq >> 4, c = qq & 15;
      const float* src = half ? (W + (size_t)(n0 + r) * K + kc + c * 4)
                              : (A + (size_t)(m0 + r) * K + kc + c * 4);
      float4 v = *(const float4*)src;
      if (half) sb[r][c] = v; else sa[r][c] = v;
    }
    __syncthreads();
#pragma unroll
    for (int c = 0; c < 16; ++c) {
      const int ks = (c + mt + nt) & 15;  // swizzle to break LDS bank conflicts
      float4 av[4], bv[4];
#pragma unroll
      for (int i = 0; i < 4; ++i) av[i] = sa[mt * 4 + i][ks];
#pragma unroll
      for (int j = 0; j < 4; ++j) bv[j] = sb[nt * 4 + j][ks];
#pragma unroll
      for (int i = 0; i < 4; ++i)
#pragma unroll
        for (int j = 0; j < 4; ++j) {
          acc[i][j] += av[i].x * bv[j].x;
          acc[i][j] += av[i].y * bv[j].y;
          acc[i][j] += av[i].z * bv[j].z;
          acc[i][j] += av[i].w * bv[j].w;
        }
    }
    __syncthreads();
  }
#pragma unroll
  for (int i = 0; i < 4; ++i)
#pragma unroll
    for (int j = 0; j < 4; ++j) {
      size_t o = (size_t)(m0 + mt * 4 + i) * Ntot + n0 + nt * 4 + j;
      float v = acc[i][j];
      if (RESID) v += Id[o];
      Out[o] = fmaxf(v, 0.0f);
    }
}

// ---------------------------------------------------------------- pad weights rows to 4-aligned cols
__global__ void k_pad_w(const float* __restrict__ src, float* __restrict__ dst,
                        int rows, int cin, int cp4) {
  int t = blockIdx.x * 256 + threadIdx.x;
  if (t >= rows * cp4) return;
  int r = t / cp4, c = t - r * cp4;
  dst[t] = (c < cin) ? src[(size_t)r * cin + c] : 0.0f;
}

// ---------------------------------------------------------------- out1 transpose (B*S,128) -> (B,128,S)
__global__ void k_out1_t(const float* __restrict__ in, float* __restrict__ out) {
  __shared__ float tile[32][33];
  const int b = blockIdx.z;
  const int s0 = blockIdx.x * 32, d0 = blockIdx.y * 32;
  const int tx = threadIdx.x, ty = threadIdx.y;
#pragma unroll
  for (int i = 0; i < 32; i += 8)
    tile[ty + i][tx] = in[(size_t)(b * SS + s0 + ty + i) * 128 + d0 + tx];
  __syncthreads();
#pragma unroll
  for (int i = 0; i < 32; i += 8)
    out[(size_t)(b * 128 + d0 + ty + i) * SS + s0 + tx] = tile[tx][ty + i];
}

// ----------------------------------------------------------------
extern "C" void kernel_launch(void* const* d_in, const int* in_sizes, int n_in,
                              void* d_out, int out_size, void* d_ws, size_t ws_size,
                              hipStream_t stream) {
  const float* pc    = (const float*)d_in[0];
  const float* pfea  = (const float*)d_in[1];
  const float* w_sa  = (const float*)d_in[2];
  const float* w_la1 = (const float*)d_in[3];
  const float* w1_1  = (const float*)d_in[4];
  const float* w2_1  = (const float*)d_in[5];
  const float* w_la2 = (const float*)d_in[6];
  const float* w1_2  = (const float*)d_in[7];
  const float* w2_2  = (const float*)d_in[8];
  float* out0 = (float*)d_out;
  float* out1 = out0 + (size_t)BB * 3 * SS;

  char* wsp = (char*)d_ws;
  size_t off = 0;
  auto alloc = [&](size_t bytes) -> void* {
    void* p = wsp + off;
    off = (off + bytes + 255) & ~(size_t)255;
    return p;
  };
  float* hbuf = (float*)alloc((size_t)BB * SS * HHV * 4);  // 16 MB; also aliased as feaT (disjoint in time)
  float* feaT = hbuf;                                      // 8 MB needed, used only before hbuf
  int*   fpsi = (int*)alloc((size_t)BB * SS * 4);
  float* ncoor = (float*)alloc((size_t)BB * SS * 3 * 4);
  int*   gi = (int*)alloc((size_t)BB * SS * GG * 4);
  float* fa = (float*)alloc((size_t)BB * SS * C2V * 4);
  float* fb = (float*)alloc((size_t)BB * SS * C2V * 4);
  float* wsap = (float*)alloc(128 * 68 * 4);
  float* wla1p = (float*)alloc(128 * 132 * 4);
  float* wla2p = (float*)alloc(128 * 132 * 4);

  k_pad_w<<<dim3((128 * 68 + 255) / 256), dim3(256), 0, stream>>>(w_sa, wsap, 128, 67, 68);
  k_pad_w<<<dim3((128 * 132 + 255) / 256), dim3(256), 0, stream>>>(w_la1, wla1p, 128, 131, 132);
  k_pad_w<<<dim3((128 * 132 + 255) / 256), dim3(256), 0, stream>>>(w_la2, wla2p, 128, 131, 132);

  k_transpose_fea<<<dim3(NN / 32, CC / 32, BB), dim3(32, 8), 0, stream>>>(pfea, feaT);
  k_fps<<<dim3(BB), dim3(1024), 0, stream>>>(pc, fpsi);
  k_gather<<<dim3((BB * SS + 255) / 256), dim3(256), 0, stream>>>(pc, fpsi, ncoor, out0);

  // stage 1: group among original N points, r=0.2
  k_knn<<<dim3(BB * SS), dim3(256), 0, stream>>>(pc, ncoor, 0, NN, 0.04f, gi);
  k_group_mlp<64><<<dim3(BB * SS / 16), dim3(256), 0, stream>>>(feaT, gi, ncoor, pc, 0, NN, 0.2f, wsap, fa);

  // shared grouping for both inv-res blocks (same points, same radius 0.4)
  k_knn<<<dim3(BB * SS), dim3(256), 0, stream>>>(ncoor, ncoor, 1, SS, 0.16f, gi);

  // inv-res block 1
  k_group_mlp<128><<<dim3(BB * SS / 16), dim3(256), 0, stream>>>(fa, gi, ncoor, ncoor, 1, SS, 0.4f, wla1p, fb);
  k_dense<false><<<dim3(128, 8), dim3(256), 0, stream>>>(fb, w1_1, nullptr, hbuf, 128, 512);
  k_dense<true><<<dim3(128, 2), dim3(256), 0, stream>>>(hbuf, w2_1, fa, fb, 512, 128);

  // inv-res block 2
  k_group_mlp<128><<<dim3(BB * SS / 16), dim3(256), 0, stream>>>(fb, gi, ncoor, ncoor, 1, SS, 0.4f, wla2p, fa);
  k_dense<false><<<dim3(128, 8), dim3(256), 0, stream>>>(fa, w1_2, nullptr, hbuf, 128, 512);
  k_dense<true><<<dim3(128, 2), dim3(256), 0, stream>>>(hbuf, w2_2, fb, fa, 512, 128);

  k_out1_t<<<dim3(SS / 32, 128 / 32, BB), dim3(32, 8), 0, stream>>>(fa, out1);
}

// Round 13
// 4112.298 us; speedup vs baseline: 1.1666x; 1.0411x over previous
//
#include <hip/hip_runtime.h>
#include <hip/hip_bf16.h>

#define BB 4
#define NN 8192
#define CC 64
#define SS 2048
#define GG 32
#define C2V 128
#define HHV 512

typedef unsigned long long u64;
typedef unsigned int u32;

// ---------------------------------------------------------------- transpose fea (B,C,N)->(B,N,C)
__global__ void k_transpose_fea(const float* __restrict__ in, float* __restrict__ out) {
  __shared__ float tile[32][33];
  const int b = blockIdx.z;
  const int n0 = blockIdx.x * 32, c0 = blockIdx.y * 32;
  const int tx = threadIdx.x, ty = threadIdx.y;
  const float* src = in + (size_t)b * CC * NN;
#pragma unroll
  for (int i = 0; i < 32; i += 8)
    tile[ty + i][tx] = src[(size_t)(c0 + ty + i) * NN + n0 + tx];
  __syncthreads();
  float* dst = out + (size_t)b * NN * CC;
#pragma unroll
  for (int i = 0; i < 32; i += 8)
    dst[(size_t)(n0 + ty + i) * CC + c0 + tx] = tile[tx][ty + i];
}

// ---------------------------------------------------------------- FPS (v8: AGPR-parked coords)
// r12's LDS-staged structure, but the per-step 6x ds_read_b128 own-coord reads
// (the dominant ~1150 cyc/step of LDS pipe time) are replaced by AGPR reads:
// the 24 coord floats per lane are parked ONCE in AGPRs via inline-asm
// v_accvgpr_write_b32 ("a" constraint) and fetched each step with
// v_accvgpr_read_b32. asm-produced values cannot be rematerialized from memory
// (the r6-r9 failure) and volatile prevents hoisting -> guaranteed register
// residency on the unified VGPR/AGPR file. LDS keeps only: key exchange,
// 3 broadcast winner-coord reads, sIdx output buffer.
// Numerics = verified r11/r12 chain (bit-identical: contract-off materialized
// squares, wave-uniform correctly-rounded sqrt, exact f64 preimage floor
// tie-break, min-index butterflies).
__global__ __launch_bounds__(1024, 4) void k_fps(const float* __restrict__ pc, int* __restrict__ fps_idx) {
#pragma clang fp contract(off)
  __shared__ float lx[NN], ly[NN], lz[NN];
  __shared__ int sIdx[SS];
  __shared__ u64 sK[2][16];
  const int b = blockIdx.x, tid = threadIdx.x;
  const int lane = tid & 63, wid = tid >> 6;
  const float* pb = pc + (size_t)b * 3 * NN;

  // ---- load own 8 points (2 float4 per axis), stage to LDS, park in AGPRs
  const float4* gx = (const float4*)pb;
  const float4* gy = (const float4*)(pb + NN);
  const float4* gz = (const float4*)(pb + 2 * NN);
  float4 vXa = gx[tid], vXb = gx[tid + 1024];
  float4 vYa = gy[tid], vYb = gy[tid + 1024];
  float4 vZa = gz[tid], vZb = gz[tid + 1024];
  {
    float4* sx = (float4*)lx; float4* sy = (float4*)ly; float4* sz = (float4*)lz;
    sx[tid] = vXa; sx[tid + 1024] = vXb;
    sy[tid] = vYa; sy[tid + 1024] = vYb;
    sz[tid] = vZa; sz[tid + 1024] = vZb;
  }
  float aXax, aXay, aXaz, aXaw, aXbx, aXby, aXbz, aXbw;
  float aYax, aYay, aYaz, aYaw, aYbx, aYby, aYbz, aYbw;
  float aZax, aZay, aZaz, aZaw, aZbx, aZby, aZbz, aZbw;
#define PARK(A, V) asm volatile("v_accvgpr_write_b32 %0, %1" : "=a"(A) : "v"(V));
  PARK(aXax, vXa.x) PARK(aXay, vXa.y) PARK(aXaz, vXa.z) PARK(aXaw, vXa.w)
  PARK(aXbx, vXb.x) PARK(aXby, vXb.y) PARK(aXbz, vXb.z) PARK(aXbw, vXb.w)
  PARK(aYax, vYa.x) PARK(aYay, vYa.y) PARK(aYaz, vYa.z) PARK(aYaw, vYa.w)
  PARK(aYbx, vYb.x) PARK(aYby, vYb.y) PARK(aYbz, vYb.z) PARK(aYbw, vYb.w)
  PARK(aZax, vZa.x) PARK(aZay, vZa.y) PARK(aZaz, vZa.z) PARK(aZaw, vZa.w)
  PARK(aZbx, vZb.x) PARK(aZby, vZb.y) PARK(aZbz, vZb.z) PARK(aZbw, vZb.w)
#undef PARK
  if (tid < 32) ((u64*)sK)[tid] = 0ull;
  if (tid == 0) sK[0][0] = ~0ull;   // step-0 winner: idx 0
  __syncthreads();

  const u32 ibase = (u32)(wid * 256 + lane * 4);  // global point index base
  float4 D0 = make_float4(1e20f, 1e20f, 1e20f, 1e20f);
  float4 D1 = D0;

#define DPPK64(K, CTL) { \
      u32 lo = (u32)(K), hi = (u32)((K) >> 32); \
      u32 lo2 = (u32)__builtin_amdgcn_update_dpp(0, (int)lo, CTL, 0xf, 0xf, false); \
      u32 hi2 = (u32)__builtin_amdgcn_update_dpp(0, (int)hi, CTL, 0xf, 0xf, false); \
      u64 k2 = ((u64)hi2 << 32) | (u64)lo2; if (k2 > (K)) (K) = k2; }
#define RMAXF(V, CTL) { \
      float t_ = __int_as_float(__builtin_amdgcn_update_dpp(0, __float_as_int(V), CTL, 0xf, 0xf, false)); \
      (V) = fmaxf((V), t_); }
#define RMINU(V, CTL) { \
      u32 t_ = (u32)__builtin_amdgcn_update_dpp(0, (int)(V), CTL, 0xf, 0xf, false); \
      (V) = min((V), t_); }
#define FETCH(V, A) asm volatile("v_accvgpr_read_b32 %0, %1" : "=v"(V) : "a"(A));

  for (int k = 0; k < SS; ++k) {
    const int p = k & 1, pn = p ^ 1;
    // ---- key read (only LDS dependency), coords come from AGPRs underneath
    u64 kk = sK[p][lane & 15];
    float xax, xay, xaz, xaw, xbx, xby, xbz, xbw;
    float yax, yay, yaz, yaw, ybx, yby, ybz, ybw;
    float zax, zay, zaz, zaw, zbx, zby, zbz, zbw;
    FETCH(xax, aXax) FETCH(xay, aXay) FETCH(xaz, aXaz) FETCH(xaw, aXaw)
    FETCH(xbx, aXbx) FETCH(xby, aXby) FETCH(xbz, aXbz) FETCH(xbw, aXbw)
    FETCH(yax, aYax) FETCH(yay, aYay) FETCH(yaz, aYaz) FETCH(yaw, aYaw)
    FETCH(ybx, aYbx) FETCH(yby, aYby) FETCH(ybz, aYbz) FETCH(ybw, aYbw)
    FETCH(zax, aZax) FETCH(zay, aZay) FETCH(zaz, aZaz) FETCH(zaw, aZaw)
    FETCH(zbx, aZbx) FETCH(zby, aZby) FETCH(zbz, aZbz) FETCH(zbw, aZbw)
    // ---- cross-wave winner (slots repeat every 16 lanes)
    DPPK64(kk, 0x121) DPPK64(kk, 0x122) DPPK64(kk, 0x124) DPPK64(kk, 0x128)
    const u32 idx = 0xFFFFFFFFu - (u32)kk;
    if (tid == 0) sIdx[k] = (int)idx;
    // winner coords: same-address LDS broadcast
    const float cx = lx[idx], cy = ly[idx], cz = lz[idx];

    // ---- squared-distance update (bitwise np: materialized squares, (t0+t1)+t2)
#define UPDC(XX, YY, ZZ, DD) { \
      float dx_ = (XX) - cx, dy_ = (YY) - cy, dz_ = (ZZ) - cz; \
      float t0_ = dx_ * dx_, t1_ = dy_ * dy_, t2_ = dz_ * dz_; \
      float s_ = (t0_ + t1_) + t2_; \
      (DD) = fminf((DD), s_); }
    UPDC(xax, yax, zax, D0.x) UPDC(xay, yay, zay, D0.y)
    UPDC(xaz, yaz, zaz, D0.z) UPDC(xaw, yaw, zaw, D0.w)
    UPDC(xbx, ybx, zbx, D1.x) UPDC(xby, yby, zby, D1.y)
    UPDC(xbz, ybz, zbz, D1.z) UPDC(xbw, ybw, zbw, D1.w)
#undef UPDC

    // ---- per-lane max of squared dists, wave butterfly on m2 (sqrt-free)
    float m2 = fmaxf(fmaxf(fmaxf(D0.x, D0.y), fmaxf(D0.z, D0.w)),
                     fmaxf(fmaxf(D1.x, D1.y), fmaxf(D1.z, D1.w)));
    RMAXF(m2, 0x121) RMAXF(m2, 0x122) RMAXF(m2, 0x124) RMAXF(m2, 0x128)
    m2 = fmaxf(m2, __shfl_xor(m2, 16, 64));
    m2 = fmaxf(m2, __shfl_xor(m2, 32, 64));   // wave max (uniform)

    // ---- wave-uniform: s = fl(sqrt(m2)), exact f64 preimage floor Lf;
    //      {D : fl(sqrt(D)) == s} == {D : D >= Lf}
    float s = sqrtf(m2);
    u32 sbits = __float_as_uint(s);
    float spred = __uint_as_float(sbits - 1u);
    double M = ((double)spred + (double)s) * 0.5;
    double L = M * M;
    if (sbits & 1u) L = __longlong_as_double(__double_as_longlong(L) + 1ll);
    float Lf = (float)L;
    if ((double)Lf < L) Lf = __uint_as_float(__float_as_uint(Lf) + 1u);

    // ---- first (smallest global index) candidate per lane: descending cascade
    u32 enc = 0xFFFFFFFFu;
    {
      int off = -1;
      if (D1.w >= Lf) off = 4096 + 3;
      if (D1.z >= Lf) off = 4096 + 2;
      if (D1.y >= Lf) off = 4096 + 1;
      if (D1.x >= Lf) off = 4096 + 0;
      if (D0.w >= Lf) off = 3;
      if (D0.z >= Lf) off = 2;
      if (D0.y >= Lf) off = 1;
      if (D0.x >= Lf) off = 0;
      if (off >= 0) enc = ibase + (u32)off;
    }
    RMINU(enc, 0x121) RMINU(enc, 0x122) RMINU(enc, 0x124) RMINU(enc, 0x128)
    enc = min(enc, (u32)__shfl_xor((int)enc, 16, 64));
    enc = min(enc, (u32)__shfl_xor((int)enc, 32, 64));

    if (lane == 0)
      sK[pn][wid] = (((u64)sbits) << 32) | (u64)(0xFFFFFFFFu - enc);
    __syncthreads();  // single barrier per step; lgkmcnt-only drain
  }
#undef DPPK64
#undef RMAXF
#undef RMINU
#undef FETCH
  // bulk writeout (coalesced)
  fps_idx[b * SS + tid] = sIdx[tid];
  fps_idx[b * SS + 1024 + tid] = sIdx[1024 + tid];
}

// ---------------------------------------------------------------- gather new_coor + out0
__global__ void k_gather(const float* __restrict__ pc, const int* __restrict__ fps_idx,
                         float* __restrict__ ncoor, float* __restrict__ out0) {
  int t = blockIdx.x * 256 + threadIdx.x;
  if (t >= BB * SS) return;
  int b = t / SS, s = t % SS;
  int id = fps_idx[t];
  const float* base = pc + (size_t)b * 3 * NN;
  float x = base[id], y = base[NN + id], z = base[2 * NN + id];
  ncoor[(size_t)t * 3] = x; ncoor[(size_t)t * 3 + 1] = y; ncoor[(size_t)t * 3 + 2] = z;
  size_t o = (size_t)b * 3 * SS + s;
  out0[o] = x; out0[o + SS] = y; out0[o + 2 * SS] = z;
}

// ---------------------------------------------------------------- kNN (k=32 within radius, fill with argmin)
// Distance replicates np's _sqdist bit-for-bit:
//   dot: np.einsum inner sum-of-products loop -> gcc -ffp-contract=fast -> FMA chain
//        acc = fma(a2,b2, fma(a1,b1, a0*b0))
//   norms: np.sum(x**2,-1) over a MATERIALIZED squares array -> pure sequential adds (no FMA)
//   d = ((-2*dot) + ||q||^2) + ||p||^2  (sequential adds, f32 throughout)
__global__ __launch_bounds__(256) void k_knn(const float* __restrict__ candp,
                                             const float* __restrict__ newc,
                                             int mode, int ncand, float r2,
                                             int* __restrict__ gidx) {
  __shared__ float cd[2048];
  __shared__ int ci[2048];
  __shared__ int hist[64];
  __shared__ int cnt, oc, binT, mlow;
  const int q = blockIdx.x, tid = threadIdx.x;
  const int b = q / SS;
  if (tid == 0) { cnt = 0; oc = 0; }
  if (tid < 64) hist[tid] = 0;
  __syncthreads();
  const float qx = newc[(size_t)q * 3], qy = newc[(size_t)q * 3 + 1], qz = newc[(size_t)q * 3 + 2];
  float qn;
  {
#pragma clang fp contract(off)
    qn = (qx * qx + qy * qy) + qz * qz;
  }
  const float sc = 64.0f / r2;
  const float* base = (mode == 0) ? candp + (size_t)b * 3 * NN : candp + (size_t)b * SS * 3;
  for (int i = tid; i < ncand; i += 256) {
    float x, y, z;
    if (mode == 0) { x = base[i]; y = base[NN + i]; z = base[2 * NN + i]; }
    else { x = base[3 * i]; y = base[3 * i + 1]; z = base[3 * i + 2]; }
    // FMA-chain dot (np einsum), contract-off norms (np materialized squares)
    float dot = fmaf(qz, z, fmaf(qy, y, qx * x));
    float d;
    {
#pragma clang fp contract(off)
      float pn = (x * x + y * y) + z * z;
      d = ((-2.0f * dot) + qn) + pn;
    }
    if (d <= r2) {
      int pp = atomicAdd(&cnt, 1);
      if (pp < 2048) { cd[pp] = d; ci[pp] = i; }
      float db = (d > 0.0f) ? d : 0.0f;
      atomicAdd(&hist[min(63, (int)(db * sc))], 1);
    }
  }
  __syncthreads();
  const int M = min(cnt, 2048);
  if (tid == 0) {
    if (M > 32) {
      int c = 0, t = 0;
      for (t = 0; t < 64; ++t) { if (c + hist[t] >= 32) break; c += hist[t]; }
      binT = t; mlow = c;
    } else binT = -1;
  }
  __syncthreads();
  int* out = gidx + (size_t)q * 32;
  if (binT < 0) {
    for (int j = tid; j < M; j += 256) out[atomicAdd(&oc, 1)] = ci[j];
    __syncthreads();
    if (tid == 0 && M < 32) {
      float bd = 1e30f; int bx = 0x7FFFFFFF;
      for (int j = 0; j < M; ++j)
        if (cd[j] < bd || (cd[j] == bd && ci[j] < bx)) { bd = cd[j]; bx = ci[j]; }
      for (int j = M; j < 32; ++j) out[j] = bx;
    }
  } else {
    const int bt = binT, m = mlow;
    for (int j = tid; j < M; j += 256) {
      float dbj = (cd[j] > 0.0f) ? cd[j] : 0.0f;
      int bin = min(63, (int)(dbj * sc));
      if (bin < bt) out[atomicAdd(&oc, 1)] = ci[j];
      else if (bin == bt) {
        int r = 0; const float dj = cd[j]; const int ij = ci[j];
        for (int kk = 0; kk < M; ++kk) {
          float dbk = (cd[kk] > 0.0f) ? cd[kk] : 0.0f;
          if (min(63, (int)(dbk * sc)) == bt &&
              (cd[kk] < dj || (cd[kk] == dj && ci[kk] < ij))) ++r;
        }
        if (m + r < 32) out[m + r] = ci[j];
      }
    }
  }
}

// ---------------------------------------------------------------- grouped MLP + max  (out 128 ch)
// grid = BB*SS/4 (2048 blocks), 4 rows/block: 2x-4x more blocks/CU than the
// old 16-row blocks -> gather latency hidden by occupancy. Per-row arithmetic
// and accumulation order unchanged.
template <int FDIM>
__global__ __launch_bounds__(256) void k_group_mlp(
    const float* __restrict__ fea, const int* __restrict__ gidx,
    const float* __restrict__ newc, const float* __restrict__ candp,
    int mode, int ncand, float radius,
    const float* __restrict__ wp, float* __restrict__ outf) {
  constexpr int CP4 = FDIM + 4;     // padded cols (67->68, 131->132)
  constexpr int NC4 = CP4 / 4;
  __shared__ float4 g4[2][32][NC4];
  __shared__ int sidx[2][32];
  __shared__ float sq[2][3];
  __shared__ float pf[2][4][128];
  const int tid = threadIdx.x;
  const int rs = tid >> 7, tl = tid & 127;
  const int dt = tl & 31, et = tl >> 5;
  const int d0 = dt * 4, e0 = et * 8;
  const int row0 = blockIdx.x * 4;
  for (int rp = 0; rp < 4; rp += 2) {
    const int row = row0 + rp + rs;
    if (tl < 32) sidx[rs][tl] = gidx[(size_t)row * 32 + tl];
    if (tl < 3) sq[rs][tl] = newc[(size_t)row * 3 + tl];
    __syncthreads();
    const int bb2 = row / SS;
    const float* fb = fea + (size_t)bb2 * ncand * FDIM;
    const float* cb = (mode == 0) ? candp + (size_t)bb2 * 3 * NN
                                  : candp + (size_t)bb2 * SS * 3;
    float* gf = (float*)&g4[rs][0][0];
    for (int qq = tl; qq < 32 * CP4; qq += 128) {
      int e = qq / CP4, c = qq - e * CP4;
      int id = sidx[rs][e];
      float v;
      if (c < FDIM) v = fb[(size_t)id * FDIM + c];
      else if (c < FDIM + 3) {
        int comp = c - FDIM;
        float pcv = (mode == 0) ? cb[(size_t)comp * NN + id] : cb[(size_t)id * 3 + comp];
        v = (pcv - sq[rs][comp]) / radius;
      } else v = 0.0f;
      gf[qq] = v;
    }
    __syncthreads();
    float acc[4][8];
#pragma unroll
    for (int i = 0; i < 4; ++i)
#pragma unroll
      for (int j = 0; j < 8; ++j) acc[i][j] = 0.0f;
    const float4* w4 = (const float4*)wp;
    for (int c4 = 0; c4 < NC4; ++c4) {
      float4 wv[4], gv[8];
#pragma unroll
      for (int i = 0; i < 4; ++i) wv[i] = w4[(size_t)(d0 + i) * NC4 + c4];
#pragma unroll
      for (int j = 0; j < 8; ++j) gv[j] = g4[rs][e0 + j][c4];
#pragma unroll
      for (int i = 0; i < 4; ++i)
#pragma unroll
        for (int j = 0; j < 8; ++j) {
          acc[i][j] += wv[i].x * gv[j].x;
          acc[i][j] += wv[i].y * gv[j].y;
          acc[i][j] += wv[i].z * gv[j].z;
          acc[i][j] += wv[i].w * gv[j].w;
        }
    }
#pragma unroll
    for (int i = 0; i < 4; ++i) {
      float m = acc[i][0];
#pragma unroll
      for (int j = 1; j < 8; ++j) m = fmaxf(m, acc[i][j]);
      pf[rs][et][d0 + i] = m;
    }
    __syncthreads();
    {
      const int d = tid & 127, r2s = tid >> 7;
      const int rowW = row0 + rp + r2s;
      float m = fmaxf(fmaxf(pf[r2s][0][d], pf[r2s][1][d]),
                      fmaxf(pf[r2s][2][d], pf[r2s][3][d]));
      outf[(size_t)rowW * 128 + d] = fmaxf(m, 0.0f);
    }
    __syncthreads();
  }
}

// ---------------------------------------------------------------- dense GEMM: Out = relu(A(M,K) * W(N,K)^T [+ Id])
template <bool RESID>
__global__ __launch_bounds__(256) void k_dense(
    const float* __restrict__ A, const float* __restrict__ W,
    const float* __restrict__ Id, float* __restrict__ Out,
    int K, int Ntot) {
  __shared__ float4 sa[64][17], sb[64][17];
  const int m0 = blockIdx.x * 64, n0 = blockIdx.y * 64;
  const int tid = threadIdx.x;
  const int mt = tid & 15, nt = tid >> 4;
  float acc[4][4];
#pragma unroll
  for (int i = 0; i < 4; ++i)
#pragma unroll
    for (int j = 0; j < 4; ++j) acc[i][j] = 0.0f;
  for (int kc = 0; kc < K; kc += 64) {
    for (int q2 = tid; q2 < 2048; q2 += 256) {
      int half = q2 >> 10, qq = q2 & 1023;
      int r = qq >> 4, c = qq & 15;
      const float* src = half ? (W + (size_t)(n0 + r) * K + kc + c * 4)
                              : (A + (size_t)(m0 + r) * K + kc + c * 4);
      float4 v = *(const float4*)src;
      if (half) sb[r][c] = v; else sa[r][c] = v;
    }
    __syncthreads();
#pragma unroll
    for (int c = 0; c < 16; ++c) {
      const int ks = (c + mt + nt) & 15;  // swizzle to break LDS bank conflicts
      float4 av[4], bv[4];
#pragma unroll
      for (int i = 0; i < 4; ++i) av[i] = sa[mt * 4 + i][ks];
#pragma unroll
      for (int j = 0; j < 4; ++j) bv[j] = sb[nt * 4 + j][ks];
#pragma unroll
      for (int i = 0; i < 4; ++i)
#pragma unroll
        for (int j = 0; j < 4; ++j) {
          acc[i][j] += av[i].x * bv[j].x;
          acc[i][j] += av[i].y * bv[j].y;
          acc[i][j] += av[i].z * bv[j].z;
          acc[i][j] += av[i].w * bv[j].w;
        }
    }
    __syncthreads();
  }
#pragma unroll
  for (int i = 0; i < 4; ++i)
#pragma unroll
    for (int j = 0; j < 4; ++j) {
      size_t o = (size_t)(m0 + mt * 4 + i) * Ntot + n0 + nt * 4 + j;
      float v = acc[i][j];
      if (RESID) v += Id[o];
      Out[o] = fmaxf(v, 0.0f);
    }
}

// ---------------------------------------------------------------- pad weights rows to 4-aligned cols
__global__ void k_pad_w(const float* __restrict__ src, float* __restrict__ dst,
                        int rows, int cin, int cp4) {
  int t = blockIdx.x * 256 + threadIdx.x;
  if (t >= rows * cp4) return;
  int r = t / cp4, c = t - r * cp4;
  dst[t] = (c < cin) ? src[(size_t)r * cin + c] : 0.0f;
}

// ---------------------------------------------------------------- out1 transpose (B*S,128) -> (B,128,S)
__global__ void k_out1_t(const float* __restrict__ in, float* __restrict__ out) {
  __shared__ float tile[32][33];
  const int b = blockIdx.z;
  const int s0 = blockIdx.x * 32, d0 = blockIdx.y * 32;
  const int tx = threadIdx.x, ty = threadIdx.y;
#pragma unroll
  for (int i = 0; i < 32; i += 8)
    tile[ty + i][tx] = in[(size_t)(b * SS + s0 + ty + i) * 128 + d0 + tx];
  __syncthreads();
#pragma unroll
  for (int i = 0; i < 32; i += 8)
    out[(size_t)(b * 128 + d0 + ty + i) * SS + s0 + tx] = tile[tx][ty + i];
}

// ----------------------------------------------------------------
extern "C" void kernel_launch(void* const* d_in, const int* in_sizes, int n_in,
                              void* d_out, int out_size, void* d_ws, size_t ws_size,
                              hipStream_t stream) {
  const float* pc    = (const float*)d_in[0];
  const float* pfea  = (const float*)d_in[1];
  const float* w_sa  = (const float*)d_in[2];
  const float* w_la1 = (const float*)d_in[3];
  const float* w1_1  = (const float*)d_in[4];
  const float* w2_1  = (const float*)d_in[5];
  const float* w_la2 = (const float*)d_in[6];
  const float* w1_2  = (const float*)d_in[7];
  const float* w2_2  = (const float*)d_in[8];
  float* out0 = (float*)d_out;
  float* out1 = out0 + (size_t)BB * 3 * SS;

  char* wsp = (char*)d_ws;
  size_t off = 0;
  auto alloc = [&](size_t bytes) -> void* {
    void* p = wsp + off;
    off = (off + bytes + 255) & ~(size_t)255;
    return p;
  };
  float* hbuf = (float*)alloc((size_t)BB * SS * HHV * 4);  // 16 MB; also aliased as feaT (disjoint in time)
  float* feaT = hbuf;                                      // 8 MB needed, used only before hbuf
  int*   fpsi = (int*)alloc((size_t)BB * SS * 4);
  float* ncoor = (float*)alloc((size_t)BB * SS * 3 * 4);
  int*   gi = (int*)alloc((size_t)BB * SS * GG * 4);
  float* fa = (float*)alloc((size_t)BB * SS * C2V * 4);
  float* fb = (float*)alloc((size_t)BB * SS * C2V * 4);
  float* wsap = (float*)alloc(128 * 68 * 4);
  float* wla1p = (float*)alloc(128 * 132 * 4);
  float* wla2p = (float*)alloc(128 * 132 * 4);

  k_pad_w<<<dim3((128 * 68 + 255) / 256), dim3(256), 0, stream>>>(w_sa, wsap, 128, 67, 68);
  k_pad_w<<<dim3((128 * 132 + 255) / 256), dim3(256), 0, stream>>>(w_la1, wla1p, 128, 131, 132);
  k_pad_w<<<dim3((128 * 132 + 255) / 256), dim3(256), 0, stream>>>(w_la2, wla2p, 128, 131, 132);

  k_transpose_fea<<<dim3(NN / 32, CC / 32, BB), dim3(32, 8), 0, stream>>>(pfea, feaT);
  k_fps<<<dim3(BB), dim3(1024), 0, stream>>>(pc, fpsi);
  k_gather<<<dim3((BB * SS + 255) / 256), dim3(256), 0, stream>>>(pc, fpsi, ncoor, out0);

  // stage 1: group among original N points, r=0.2
  k_knn<<<dim3(BB * SS), dim3(256), 0, stream>>>(pc, ncoor, 0, NN, 0.04f, gi);
  k_group_mlp<64><<<dim3(BB * SS / 4), dim3(256), 0, stream>>>(feaT, gi, ncoor, pc, 0, NN, 0.2f, wsap, fa);

  // shared grouping for both inv-res blocks (same points, same radius 0.4)
  k_knn<<<dim3(BB * SS), dim3(256), 0, stream>>>(ncoor, ncoor, 1, SS, 0.16f, gi);

  // inv-res block 1
  k_group_mlp<128><<<dim3(BB * SS / 4), dim3(256), 0, stream>>>(fa, gi, ncoor, ncoor, 1, SS, 0.4f, wla1p, fb);
  k_dense<false><<<dim3(128, 8), dim3(256), 0, stream>>>(fb, w1_1, nullptr, hbuf, 128, 512);
  k_dense<true><<<dim3(128, 2), dim3(256), 0, stream>>>(hbuf, w2_1, fa, fb, 512, 128);

  // inv-res block 2
  k_group_mlp<128><<<dim3(BB * SS / 4), dim3(256), 0, stream>>>(fb, gi, ncoor, ncoor, 1, SS, 0.4f, wla2p, fa);
  k_dense<false><<<dim3(128, 8), dim3(256), 0, stream>>>(fa, w1_2, nullptr, hbuf, 128, 512);
  k_dense<true><<<dim3(128, 2), dim3(256), 0, stream>>>(hbuf, w2_2, fb, fa, 512, 128);

  k_out1_t<<<dim3(SS / 32, 128 / 32, BB), dim3(32, 8), 0, stream>>>(fa, out1);
}